// Round 3
// baseline (1547.038 us; speedup 1.0000x reference)
//
#include <hip/hip_runtime.h>
#include <hip/hip_bf16.h>

typedef __hip_bfloat16 bf16;

#define HWp 9216
#define Wd  96
#define Hd  96
#define Bn  8
#define Cn  256
#define IMG ((size_t)Cn * HWp)          // 2,359,296 elements per image

typedef __attribute__((ext_vector_type(8))) short  s16x8;
typedef __attribute__((ext_vector_type(8))) ushort u16x8;
typedef __attribute__((ext_vector_type(4))) float  f32x4;

// Load element i of a d_in-derived array; flag==1 -> fp32, flag==0 -> bf16.
__device__ __forceinline__ float ldf(const void* p, size_t i, int flag) {
    return flag ? ((const float*)p)[i] : __bfloat162float(((const bf16*)p)[i]);
}
template <int FLAG>
__device__ __forceinline__ float ldT(const void* p, size_t i) {
    return FLAG ? ((const float*)p)[i] : __bfloat162float(((const bf16*)p)[i]);
}

// fp32 -> bf16 bits, round-to-nearest-even (finite data only).
__device__ __forceinline__ ushort bf16_rne(float f) {
    unsigned u = __float_as_uint(f);
    unsigned r = (u + 0x7fffu + ((u >> 16) & 1u)) >> 16;
    return (ushort)r;
}
__device__ __forceinline__ float bf16_hi_f(ushort h) {
    return __uint_as_float((unsigned)h << 16);
}

// ---------------------------------------------------------------------------
// Kernel 0: input dtype probe (fp32 expected; bf16 fallback kept as insurance)
// ---------------------------------------------------------------------------
__global__ void detect_dtype(const void* x, int* flag) {
    __shared__ int cnt;
    if (threadIdx.x == 0) cnt = 0;
    __syncthreads();
    const bf16* p = (const bf16*)x;
    int local = 0;
    #pragma unroll
    for (int k = 0; k < 16; ++k) {
        float w = __bfloat162float(p[threadIdx.x * 16 + k]);
        if (!(fabsf(w) < 1000.f)) local++;
    }
    atomicAdd(&cnt, local);
    __syncthreads();
    if (threadIdx.x == 0) *flag = (cnt > 64) ? 1 : 0;
}

// ---------------------------------------------------------------------------
// Kernel 1 v2: dwconv3x3 + BN + ReLU, both branches; latency-optimized.
//  - unconditional clamped tap loads, validity folded via cndmask (no exec
//    juggling around the 288 per-thread loads)
//  - dtype flag hoisted to ONE uniform branch (templated body)
//  - 32-px tile, 4 channel-quarter passes; stores transposed through an
//    XOR-swizzled LDS buffer -> 128B-contiguous global stores (kills the
//    2x write amplification seen in rocprof: WRITE 214MB vs 113MB logical)
// ---------------------------------------------------------------------------
template <int FLAG>
__device__ __forceinline__ void dw_body(
    float (*sParQ)[24], ushort (*sT)[32][64],
    const void* __restrict__ x, size_t xbase,
    const void* __restrict__ ow, const void* __restrict__ obias,
    const void* __restrict__ og, const void* __restrict__ obeta,
    const void* __restrict__ om, const void* __restrict__ ov,
    const void* __restrict__ aw, const void* __restrict__ abias,
    const void* __restrict__ ag, const void* __restrict__ abeta,
    const void* __restrict__ am, const void* __restrict__ av,
    ushort* __restrict__ tOh, ushort* __restrict__ tOl,
    ushort* __restrict__ tAh, ushort* __restrict__ tAl,
    ushort* __restrict__ Xh,  ushort* __restrict__ Xl)
{
    const int tid = threadIdx.x;
    const int pl  = tid & 31;                 // pixel within tile
    const int cs  = tid >> 5;                 // channel octet 0..7
    const int px0 = blockIdx.x * 32;          // chunk-local pixel base
    const int gpx = px0 + pl;                 // 9216 % 32 == 0: no image cross
    const int img = gpx / HWp;
    const int hw  = gpx % HWp;
    const int i   = hw / Wd, j = hw % Wd;

    int  idxk[9];
    bool mk[9];
    #pragma unroll
    for (int k = 0; k < 9; ++k) {
        int di = k / 3 - 1, dj = k % 3 - 1;
        int ii = i + di, jj = j + dj;
        mk[k]   = (ii >= 0) & (ii < Hd) & (jj >= 0) & (jj < Wd);
        idxk[k] = min(max(ii, 0), Hd - 1) * Wd + min(max(jj, 0), Wd - 1);
    }
    const size_t xibase = xbase + (size_t)img * IMG;

    ushort* plane[6] = {tOh, tOl, tAh, tAl, Xh, Xl};   // static-indexed only

    for (int q = 0; q < 4; ++q) {
        // ---- stage params for channels q*64 .. q*64+63
        for (int t = tid; t < 576; t += 256) {
            int c = t / 9, kk = t % 9;
            sParQ[c][kk]   = ldT<FLAG>(ow, (size_t)(q * 64 + c) * 9 + kk);
            sParQ[c][9+kk] = ldT<FLAG>(aw, (size_t)(q * 64 + c) * 9 + kk);
        }
        if (tid < 64) {
            int c = q * 64 + tid;
            float sco = ldT<FLAG>(og, c) * rsqrtf(ldT<FLAG>(ov, c) + 1e-5f);
            float sca = ldT<FLAG>(ag, c) * rsqrtf(ldT<FLAG>(av, c) + 1e-5f);
            sParQ[tid][18] = sco;
            sParQ[tid][19] = (ldT<FLAG>(obias, c) - ldT<FLAG>(om, c)) * sco + ldT<FLAG>(obeta, c);
            sParQ[tid][20] = sca;
            sParQ[tid][21] = (ldT<FLAG>(abias, c) - ldT<FLAG>(am, c)) * sca + ldT<FLAG>(abeta, c);
        }
        __syncthreads();

        // ---- compute this thread's 8 channels (octet cs of quarter q)
        u16x8 r[6];
        #pragma unroll
        for (int cc = 0; cc < 8; ++cc) {
            int    cl = cs * 8 + cc;
            size_t b  = xibase + (size_t)(q * 64 + cl) * HWp;
            float xv[9];
            #pragma unroll
            for (int k = 0; k < 9; ++k) xv[k] = ldT<FLAG>(x, b + idxk[k]);
            float so = 0.f, sa = 0.f;
            #pragma unroll
            for (int k = 0; k < 9; ++k) {
                float xm = mk[k] ? xv[k] : 0.f;       // cndmask, no branch
                so = fmaf(xm, sParQ[cl][k],     so);
                sa = fmaf(xm, sParQ[cl][9 + k], sa);
            }
            float xc = xv[4];                          // center tap always valid
            float to = fmaxf(fmaf(so, sParQ[cl][18], sParQ[cl][19]), 0.f);
            float ta = fmaxf(fmaf(sa, sParQ[cl][20], sParQ[cl][21]), 0.f);
            ushort h;
            h = bf16_rne(to); r[0][cc] = h; r[1][cc] = bf16_rne(to - bf16_hi_f(h));
            h = bf16_rne(ta); r[2][cc] = h; r[3][cc] = bf16_rne(ta - bf16_hi_f(h));
            h = bf16_rne(xc); r[4][cc] = h; r[5][cc] = bf16_rne(xc - bf16_hi_f(h));
        }

        // ---- transpose-store via swizzled LDS, 2 rounds x 3 planes
        const int wchunk = cs ^ (pl & 7);              // XOR bank swizzle
        #pragma unroll
        for (int rr = 0; rr < 2; ++rr) {
            #pragma unroll
            for (int pp = 0; pp < 3; ++pp)
                *(u16x8*)&sT[pp][pl][wchunk * 8] = r[rr * 3 + pp];
            __syncthreads();
            #pragma unroll
            for (int jj = 0; jj < 3; ++jj) {
                int px     = tid >> 3;                 // 0..31
                int chunk  = tid & 7;
                int rchunk = chunk ^ (px & 7);
                u16x8 v = *(const u16x8*)&sT[jj][px][rchunk * 8];
                *(u16x8*)&plane[rr * 3 + jj][(size_t)(px0 + px) * 256 + q * 64 + chunk * 8] = v;
            }
            __syncthreads();
        }
    }
}

__global__ __launch_bounds__(256, 4) void dwconv_bn_relu_hwc(
    const void* __restrict__ x, size_t xbase,
    const void* __restrict__ ow, const void* __restrict__ obias,
    const void* __restrict__ og, const void* __restrict__ obeta,
    const void* __restrict__ om, const void* __restrict__ ov,
    const void* __restrict__ aw, const void* __restrict__ abias,
    const void* __restrict__ ag, const void* __restrict__ abeta,
    const void* __restrict__ am, const void* __restrict__ av,
    ushort* __restrict__ tOh, ushort* __restrict__ tOl,
    ushort* __restrict__ tAh, ushort* __restrict__ tAl,
    ushort* __restrict__ Xh,  ushort* __restrict__ Xl,
    const int* __restrict__ flagp)
{
    __shared__ float  sParQ[64][24];
    __shared__ ushort sT[3][32][64];
    if (*flagp)
        dw_body<1>(sParQ, sT, x, xbase, ow, obias, og, obeta, om, ov,
                   aw, abias, ag, abeta, am, av, tOh, tOl, tAh, tAl, Xh, Xl);
    else
        dw_body<0>(sParQ, sT, x, xbase, ow, obias, og, obeta, om, ov,
                   aw, abias, ag, abeta, am, av, tOh, tOl, tAh, tAl, Xh, Xl);
}

// ---------------------------------------------------------------------------
// MFMA 1x1-conv GEMM, K=256, bf16x2 split (hi/lo; 3 MFMAs/k-tile -> ~18-bit
// effective input mantissa). A: HWC bf16 planes [px][256] (hi, lo).
// W: d_in fp32/bf16 [COUT][256]. Tile 64 px x 64 out; wave owns 16 outs.
// No LDS, no barriers. COUT=32 launched with 128 threads (2 waves).
// A-frag and B-frag lane layouts are mutual transposes -> swapping mfma
// operand order yields D^T: used for the CHW-output (+residual) final conv.
// ---------------------------------------------------------------------------
template <int COUT, int ACT, bool RES, bool OUTHWC>
__global__ __launch_bounds__(256) void gemm_mfma(
    const ushort* __restrict__ Ah, const ushort* __restrict__ Al,
    const void* __restrict__ w, const void* __restrict__ bias,
    const void* __restrict__ res, size_t res_base,
    float* __restrict__ out, const int* __restrict__ flagp)
{
    constexpr int NTO = (COUT + 63) / 64;
    const int flag = *flagp;
    const int lane = threadIdx.x & 63;
    const int wv   = threadIdx.x >> 6;
    const int ot   = blockIdx.x % NTO;     // o fastest: adjacent blocks share A tile
    const int pt   = blockIdx.x / NTO;
    const int px0  = pt * 64;
    const int ob   = ot * 64 + wv * 16;
    if (ob >= COUT) return;

    const int lr = lane & 15;
    const int lk = lane >> 4;

    // ---- weight fragments, hi/lo
    s16x8 wh[8], wl[8];
    {
        const size_t wrow = (size_t)(ob + lr) * 256 + lk * 8;
        #pragma unroll
        for (int kk = 0; kk < 8; ++kk) {
            float f[8];
            if (flag) {
                float4 v0 = *(const float4*)((const float*)w + wrow + kk * 32);
                float4 v1 = *(const float4*)((const float*)w + wrow + kk * 32 + 4);
                f[0]=v0.x; f[1]=v0.y; f[2]=v0.z; f[3]=v0.w;
                f[4]=v1.x; f[5]=v1.y; f[6]=v1.z; f[7]=v1.w;
            } else {
                #pragma unroll
                for (int i = 0; i < 8; ++i)
                    f[i] = __bfloat162float(((const bf16*)w)[wrow + kk * 32 + i]);
            }
            #pragma unroll
            for (int i = 0; i < 8; ++i) {
                ushort h = bf16_rne(f[i]);
                wh[kk][i] = (short)h;
                wl[kk][i] = (short)bf16_rne(f[i] - bf16_hi_f(h));
            }
        }
    }

    f32x4 acc[4] = {};
    #pragma unroll
    for (int m = 0; m < 4; ++m) {
        const size_t arow = (size_t)(px0 + m * 16 + lr) * 256 + lk * 8;
        #pragma unroll
        for (int kk = 0; kk < 8; ++kk) {
            s16x8 ah = *(const s16x8*)(Ah + arow + kk * 32);
            s16x8 al = *(const s16x8*)(Al + arow + kk * 32);
            if (OUTHWC) {
                acc[m] = __builtin_amdgcn_mfma_f32_16x16x32_bf16(ah, wh[kk], acc[m], 0, 0, 0);
                acc[m] = __builtin_amdgcn_mfma_f32_16x16x32_bf16(ah, wl[kk], acc[m], 0, 0, 0);
                acc[m] = __builtin_amdgcn_mfma_f32_16x16x32_bf16(al, wh[kk], acc[m], 0, 0, 0);
            } else {
                acc[m] = __builtin_amdgcn_mfma_f32_16x16x32_bf16(wh[kk], ah, acc[m], 0, 0, 0);
                acc[m] = __builtin_amdgcn_mfma_f32_16x16x32_bf16(wl[kk], ah, acc[m], 0, 0, 0);
                acc[m] = __builtin_amdgcn_mfma_f32_16x16x32_bf16(wh[kk], al, acc[m], 0, 0, 0);
            }
        }
    }

    if (OUTHWC) {
        // D: row=px (lk*4+r within m-frag), col=o (lr)
        int o = ob + lr;
        float bv = ldf(bias, o, flag);
        #pragma unroll
        for (int m = 0; m < 4; ++m) {
            #pragma unroll
            for (int r = 0; r < 4; ++r) {
                int px = px0 + m * 16 + lk * 4 + r;
                float v = acc[m][r] + bv;
                if (ACT == 1) v = 1.f / (1.f + __expf(-v));
                out[(size_t)px * COUT + o] = v;
            }
        }
    } else {
        // Swapped operands: D row=o (lk*4+r), col=px (lr). CHW out + residual.
        int img = px0 / HWp;
        int hwb = px0 % HWp;
        #pragma unroll
        for (int r = 0; r < 4; ++r) {
            int o = ob + lk * 4 + r;
            float bv = ldf(bias, o, flag);
            #pragma unroll
            for (int m = 0; m < 4; ++m) {
                int hw = hwb + m * 16 + lr;
                size_t oidx = (size_t)img * IMG + (size_t)o * HWp + hw;
                float v = acc[m][r] + bv;
                if (RES) v += ldf(res, res_base + oidx, flag);
                out[oidx] = v;
            }
        }
    }
}

// ---------------------------------------------------------------------------
// Kernel 5: deformable bilinear sampling + attention sum, channel-last.
// Epilogue emits bf16 hi/lo HWC planes so the final projection runs on MFMA.
// ---------------------------------------------------------------------------
__global__ __launch_bounds__(256) void deform_sample_hwc(
    const float* __restrict__ value,
    const float* __restrict__ offset,
    const float* __restrict__ attn,
    ushort* __restrict__ outh, ushort* __restrict__ outl)
{
    __shared__ int   sIdx[16 * 32 * 4];   // [pix][n*4+p][tap]
    __shared__ float sWt [16 * 32 * 4];

    int tid  = threadIdx.x;
    int pix0 = blockIdx.x * 16;           // chunk-local pixel base

    // ---- phase 1: tap precompute --------------------------------------
    #pragma unroll
    for (int it = 0; it < 2; ++it) {
        int task = it * 256 + tid;        // 512 tasks
        int pix  = task >> 5;             // 0..15
        int np   = task & 31;             // n*4+p
        int gpix = pix0 + pix;
        int hw   = gpix % HWp;
        int i    = hw / Wd;
        int j    = hw % Wd;
        float ox = offset[(size_t)gpix * 64 + np * 2];
        float oy = offset[(size_t)gpix * 64 + np * 2 + 1];
        float a  = attn[(size_t)gpix * 32 + np];
        float ix = (float)j + 0.5f + ox * 47.5f;
        float iy = (float)i + 0.5f + oy * 47.5f;
        float x0 = floorf(ix), y0 = floorf(iy);
        float wx1 = ix - x0, wy1 = iy - y0;
        float wx0 = 1.f - wx1, wy0 = 1.f - wy1;
        int base = task * 4;
        #pragma unroll
        for (int t = 0; t < 4; ++t) {
            float xc = (t & 1) ? x0 + 1.f : x0;
            float yc = (t & 2) ? y0 + 1.f : y0;
            float wt = ((t & 1) ? wx1 : wx0) * ((t & 2) ? wy1 : wy0);
            bool ok  = (xc >= 0.f) & (xc <= 95.f) & (yc >= 0.f) & (yc <= 95.f);
            int xi = min(max((int)xc, 0), 95);
            int yi = min(max((int)yc, 0), 95);
            sIdx[base + t] = yi * Wd + xi;
            sWt [base + t] = ok ? a * wt : 0.f;
        }
    }
    __syncthreads();

    // ---- phase 2: gather + accumulate ---------------------------------
    int c   = tid;                        // 0..255
    int n   = c >> 5;                     // head
    int img = pix0 / HWp;                 // tiles never cross image
    const float* vbase = value + (size_t)img * HWp * 256;

    #pragma unroll 4
    for (int pix = 0; pix < 16; ++pix) {
        int base = (pix * 32 + n * 4) * 4;
        float acc = 0.f;
        #pragma unroll
        for (int p = 0; p < 4; ++p) {
            float4 w4 = *(const float4*)&sWt [base + p * 4];
            int4   i4 = *(const int4*)  &sIdx[base + p * 4];
            acc += w4.x * vbase[(size_t)i4.x * 256 + c];
            acc += w4.y * vbase[(size_t)i4.y * 256 + c];
            acc += w4.z * vbase[(size_t)i4.z * 256 + c];
            acc += w4.w * vbase[(size_t)i4.w * 256 + c];
        }
        ushort h = bf16_rne(acc);
        ushort l = bf16_rne(acc - bf16_hi_f(h));
        size_t o = (size_t)(pix0 + pix) * 256 + c;
        outh[o] = h;
        outl[o] = l;
    }
}

// ---------------------------------------------------------------------------
// Chunked pipeline. Per-image ws: 6 bf16 planes (tOh,tOl,tAh,tAl,Xh,Xl) +
// offset f32 + attn f32 = 31.85 MB. Vf (value, f32 HWC) ALIASES tAh/tAl
// (dead after step 3; identical byte size) -> k=8 fits in ~243 MiB.
// Sh/Sl reuse tOh/tOl after step 2. d_out written only by the final kernel.
// ---------------------------------------------------------------------------
extern "C" void kernel_launch(void* const* d_in, const int* in_sizes, int n_in,
                              void* d_out, int out_size, void* d_ws, size_t ws_size,
                              hipStream_t stream)
{
    const void* x        = d_in[0];
    const void* off_dw_w = d_in[1];
    const void* off_dw_b = d_in[2];
    const void* off_bn_g = d_in[3];
    const void* off_bn_b = d_in[4];
    const void* off_bn_m = d_in[5];
    const void* off_bn_v = d_in[6];
    const void* off_pw_w = d_in[7];
    const void* off_pw_b = d_in[8];
    const void* att_dw_w = d_in[9];
    const void* att_dw_b = d_in[10];
    const void* att_bn_g = d_in[11];
    const void* att_bn_b = d_in[12];
    const void* att_bn_m = d_in[13];
    const void* att_bn_v = d_in[14];
    const void* att_pw_w = d_in[15];
    const void* att_pw_b = d_in[16];
    const void* val_w    = d_in[17];
    const void* val_b    = d_in[18];
    const void* out_w    = d_in[19];
    const void* out_b    = d_in[20];

    const size_t perImg = 6 * IMG * 2          // bf16 hi/lo planes
                        + (size_t)HWp * 64 * 4 // offset fp32 HWC
                        + (size_t)HWp * 32 * 4;// attn fp32 HWC
    int k = 1;
    if      (ws_size >= 256 + 8 * perImg) k = 8;
    else if (ws_size >= 256 + 4 * perImg) k = 4;
    else if (ws_size >= 256 + 2 * perImg) k = 2;

    char* ws = (char*)d_ws;
    int*    flag = (int*)ws;
    const size_t kIMG = (size_t)k * IMG;
    ushort* tOh = (ushort*)(ws + 256);         // also Sh after step 5
    ushort* tOl = tOh + kIMG;                  // also Sl
    ushort* tAh = tOl + kIMG;                  // also Vf (f32) after step 3
    ushort* tAl = tAh + kIMG;
    ushort* Xh  = tAl + kIMG;
    ushort* Xl  = Xh  + kIMG;
    float*  Vf  = (float*)tAh;                 // alias: kIMG f32 == 2*kIMG bf16
    float*  OFF = (float*)(Xl + kIMG);
    float*  ATT = OFF + (size_t)k * HWp * 64;

    detect_dtype<<<1, 256, 0, stream>>>(x, flag);

    const int nPx   = k * 144;                 // 64-px GEMM tiles
    const int nDw   = k * 288;                 // 32-px dwconv tiles
    const int nDef  = k * (HWp / 16);

    for (int b0 = 0; b0 < Bn; b0 += k) {
        size_t xelem = (size_t)b0 * IMG;
        float* outp  = (float*)d_out + xelem;

        // 1. dwconv+BN+ReLU both branches; emit t_off/t_att/x as HWC bf16x2
        dwconv_bn_relu_hwc<<<nDw, 256, 0, stream>>>(
            x, xelem,
            off_dw_w, off_dw_b, off_bn_g, off_bn_b, off_bn_m, off_bn_v,
            att_dw_w, att_dw_b, att_bn_g, att_bn_b, att_bn_m, att_bn_v,
            tOh, tOl, tAh, tAl, Xh, Xl, flag);

        // 2. offset = t_off @ off_pw^T  (64 ch, HWC fp32)
        gemm_mfma<64, 0, false, true><<<nPx, 256, 0, stream>>>(
            tOh, tOl, off_pw_w, off_pw_b, nullptr, 0, OFF, flag);

        // 3. attn = sigmoid(t_att @ att_pw^T)  (32 ch, HWC fp32; 2 waves)
        gemm_mfma<32, 1, false, true><<<nPx, 128, 0, stream>>>(
            tAh, tAl, att_pw_w, att_pw_b, nullptr, 0, ATT, flag);

        // 4. value = x @ val_w^T  (256 ch, HWC fp32) -> Vf (aliases tAh/tAl)
        gemm_mfma<256, 0, false, true><<<nPx * 4, 256, 0, stream>>>(
            Xh, Xl, val_w, val_b, nullptr, 0, Vf, flag);

        // 5. deformable sampling + attention sum -> Sh/Sl (reuse tOh/tOl)
        deform_sample_hwc<<<nDef, 256, 0, stream>>>(Vf, OFF, ATT, tOh, tOl);

        // 6. final projection + bias + residual -> d_out (fp32 CHW)
        gemm_mfma<256, 0, true, false><<<nPx * 4, 256, 0, stream>>>(
            tOh, tOl, out_w, out_b, x, xelem, outp, flag);
    }
}

// Round 4
// 1124.200 us; speedup vs baseline: 1.3761x; 1.3761x over previous
//
#include <hip/hip_runtime.h>
#include <hip/hip_bf16.h>

typedef __hip_bfloat16 bf16;

#define HWp 9216
#define Wd  96
#define Hd  96
#define Bn  8
#define Cn  256
#define IMG ((size_t)Cn * HWp)          // 2,359,296 elements per image

typedef __attribute__((ext_vector_type(8))) short  s16x8;
typedef __attribute__((ext_vector_type(8))) ushort u16x8;
typedef __attribute__((ext_vector_type(4))) float  f32x4;

// Load element i of a d_in-derived array; flag==1 -> fp32, flag==0 -> bf16.
__device__ __forceinline__ float ldf(const void* p, size_t i, int flag) {
    return flag ? ((const float*)p)[i] : __bfloat162float(((const bf16*)p)[i]);
}
template <int FLAG>
__device__ __forceinline__ float ldT(const void* p, size_t i) {
    return FLAG ? ((const float*)p)[i] : __bfloat162float(((const bf16*)p)[i]);
}

// fp32 -> bf16 bits, round-to-nearest-even (finite data only).
__device__ __forceinline__ ushort bf16_rne(float f) {
    unsigned u = __float_as_uint(f);
    unsigned r = (u + 0x7fffu + ((u >> 16) & 1u)) >> 16;
    return (ushort)r;
}
__device__ __forceinline__ float bf16_hi_f(ushort h) {
    return __uint_as_float((unsigned)h << 16);
}

// ---------------------------------------------------------------------------
// Kernel 0: input dtype probe (fp32 expected; bf16 fallback kept as insurance)
// ---------------------------------------------------------------------------
__global__ void detect_dtype(const void* x, int* flag) {
    __shared__ int cnt;
    if (threadIdx.x == 0) cnt = 0;
    __syncthreads();
    const bf16* p = (const bf16*)x;
    int local = 0;
    #pragma unroll
    for (int k = 0; k < 16; ++k) {
        float w = __bfloat162float(p[threadIdx.x * 16 + k]);
        if (!(fabsf(w) < 1000.f)) local++;
    }
    atomicAdd(&cnt, local);
    __syncthreads();
    if (threadIdx.x == 0) *flag = (cnt > 64) ? 1 : 0;
}

// ---------------------------------------------------------------------------
// Kernel 1 v3: dwconv3x3 + BN + ReLU, both branches.
// v1 structure (64-px tile, thread=(pixel, ch-group), direct u16x8 stores so
// each pixel's 512B HWC row is fully dirtied within one block's tight window
// -> no partial-line write-allocate storm, the v2 regression).
// Plus v2's fixes: templated dtype flag (one uniform branch) and
// unconditional clamped tap loads with cndmask validity (full MLP).
// ---------------------------------------------------------------------------
template <int FLAG>
__device__ __forceinline__ void dw_body(
    float (*sPar)[24],
    const void* __restrict__ x, size_t xbase,
    const void* __restrict__ ow, const void* __restrict__ obias,
    const void* __restrict__ og, const void* __restrict__ obeta,
    const void* __restrict__ om, const void* __restrict__ ov,
    const void* __restrict__ aw, const void* __restrict__ abias,
    const void* __restrict__ ag, const void* __restrict__ abeta,
    const void* __restrict__ am, const void* __restrict__ av,
    ushort* __restrict__ tOh, ushort* __restrict__ tOl,
    ushort* __restrict__ tAh, ushort* __restrict__ tAl,
    ushort* __restrict__ Xh,  ushort* __restrict__ Xl)
{
    const int tid = threadIdx.x;

    for (int t = tid; t < 2304; t += 256) {
        int c = t / 9, k = t % 9;
        sPar[c][k]     = ldT<FLAG>(ow, t);
        sPar[c][9 + k] = ldT<FLAG>(aw, t);
    }
    {
        int c = tid;
        float sco = ldT<FLAG>(og, c) * rsqrtf(ldT<FLAG>(ov, c) + 1e-5f);
        float sca = ldT<FLAG>(ag, c) * rsqrtf(ldT<FLAG>(av, c) + 1e-5f);
        sPar[c][18] = sco;
        sPar[c][19] = (ldT<FLAG>(obias, c) - ldT<FLAG>(om, c)) * sco + ldT<FLAG>(obeta, c);
        sPar[c][20] = sca;
        sPar[c][21] = (ldT<FLAG>(abias, c) - ldT<FLAG>(am, c)) * sca + ldT<FLAG>(abeta, c);
    }
    __syncthreads();

    const int pl  = tid & 63;
    const int cg  = tid >> 6;                 // channel group: 64 ch each
    const int gpx = blockIdx.x * 64 + pl;     // 9216 % 64 == 0: no image cross
    const int img = gpx / HWp;
    const int hw  = gpx % HWp;
    const int i   = hw / Wd, j = hw % Wd;

    int  idxk[9];
    bool mk[9];
    #pragma unroll
    for (int k = 0; k < 9; ++k) {
        int di = k / 3 - 1, dj = k % 3 - 1;
        int ii = i + di, jj = j + dj;
        mk[k]   = (ii >= 0) & (ii < Hd) & (jj >= 0) & (jj < Wd);
        idxk[k] = min(max(ii, 0), Hd - 1) * Wd + min(max(jj, 0), Wd - 1);
    }

    const size_t pbase = xbase + (size_t)img * IMG + (size_t)(cg * 64) * HWp;
    const size_t obase = (size_t)gpx * 256 + cg * 64;

    #pragma unroll 1
    for (int c8 = 0; c8 < 8; ++c8) {
        u16x8 voh, vol, vah, vAl, vxh, vxl;
        #pragma unroll
        for (int cc = 0; cc < 8; ++cc) {
            int    c = cg * 64 + c8 * 8 + cc;
            size_t b = pbase + (size_t)(c8 * 8 + cc) * HWp;
            float xv[9];
            #pragma unroll
            for (int k = 0; k < 9; ++k) xv[k] = ldT<FLAG>(x, b + idxk[k]);
            float so = 0.f, sa = 0.f;
            #pragma unroll
            for (int k = 0; k < 9; ++k) {
                float xm = mk[k] ? xv[k] : 0.f;       // cndmask, no branch
                so = fmaf(xm, sPar[c][k],     so);
                sa = fmaf(xm, sPar[c][9 + k], sa);
            }
            float xc = xv[4];                          // center tap, always valid
            float to = fmaxf(fmaf(so, sPar[c][18], sPar[c][19]), 0.f);
            float ta = fmaxf(fmaf(sa, sPar[c][20], sPar[c][21]), 0.f);
            ushort h;
            h = bf16_rne(to); voh[cc] = h; vol[cc] = bf16_rne(to - bf16_hi_f(h));
            h = bf16_rne(ta); vah[cc] = h; vAl[cc] = bf16_rne(ta - bf16_hi_f(h));
            h = bf16_rne(xc); vxh[cc] = h; vxl[cc] = bf16_rne(xc - bf16_hi_f(h));
        }
        size_t o = obase + c8 * 8;
        *(u16x8*)(tOh + o) = voh;  *(u16x8*)(tOl + o) = vol;
        *(u16x8*)(tAh + o) = vah;  *(u16x8*)(tAl + o) = vAl;
        *(u16x8*)(Xh  + o) = vxh;  *(u16x8*)(Xl  + o) = vxl;
    }
}

__global__ __launch_bounds__(256) void dwconv_bn_relu_hwc(
    const void* __restrict__ x, size_t xbase,
    const void* __restrict__ ow, const void* __restrict__ obias,
    const void* __restrict__ og, const void* __restrict__ obeta,
    const void* __restrict__ om, const void* __restrict__ ov,
    const void* __restrict__ aw, const void* __restrict__ abias,
    const void* __restrict__ ag, const void* __restrict__ abeta,
    const void* __restrict__ am, const void* __restrict__ av,
    ushort* __restrict__ tOh, ushort* __restrict__ tOl,
    ushort* __restrict__ tAh, ushort* __restrict__ tAl,
    ushort* __restrict__ Xh,  ushort* __restrict__ Xl,
    const int* __restrict__ flagp)
{
    __shared__ float sPar[256][24];
    if (*flagp)
        dw_body<1>(sPar, x, xbase, ow, obias, og, obeta, om, ov,
                   aw, abias, ag, abeta, am, av, tOh, tOl, tAh, tAl, Xh, Xl);
    else
        dw_body<0>(sPar, x, xbase, ow, obias, og, obeta, om, ov,
                   aw, abias, ag, abeta, am, av, tOh, tOl, tAh, tAl, Xh, Xl);
}

// ---------------------------------------------------------------------------
// MFMA 1x1-conv GEMM, K=256, bf16x2 split (hi/lo; 3 MFMAs/k-tile -> ~18-bit
// effective input mantissa). A: HWC bf16 planes [px][256] (hi, lo).
// W: d_in fp32/bf16 [COUT][256]. Tile 64 px x 64 out; wave owns 16 outs.
// No LDS, no barriers. COUT=32 launched with 128 threads (2 waves).
// NTO==4: XCD-aware swizzle so the 4 o-tiles sharing one A px-tile land on
// the SAME XCD (round-robin heuristic: xcd = blockIdx % 8) -> A L2-reused.
// A-frag and B-frag lane layouts are mutual transposes -> swapping mfma
// operand order yields D^T: used for the CHW-output (+residual) final conv.
// ---------------------------------------------------------------------------
template <int COUT, int ACT, bool RES, bool OUTHWC>
__global__ __launch_bounds__(256) void gemm_mfma(
    const ushort* __restrict__ Ah, const ushort* __restrict__ Al,
    const void* __restrict__ w, const void* __restrict__ bias,
    const void* __restrict__ res, size_t res_base,
    float* __restrict__ out, const int* __restrict__ flagp)
{
    constexpr int NTO = (COUT + 63) / 64;
    const int flag = *flagp;
    const int lane = threadIdx.x & 63;
    const int wv   = threadIdx.x >> 6;

    int pt, ot;
    if constexpr (NTO == 4) {
        // grid = nPx*4, always divisible by 32. b = 8g + xcd.
        // ot = g&3, pt = xcd + 8*(g>>2): the 4 blocks sharing pt differ only
        // in ot and have identical (b&7) -> same XCD under round-robin.
        int b = blockIdx.x, g = b >> 3, xcd = b & 7;
        ot = g & 3;
        pt = xcd + 8 * (g >> 2);
    } else {
        ot = 0;
        pt = blockIdx.x;
    }
    const int px0 = pt * 64;
    const int ob  = ot * 64 + wv * 16;
    if (ob >= COUT) return;

    const int lr = lane & 15;
    const int lk = lane >> 4;

    // ---- weight fragments, hi/lo
    s16x8 wh[8], wl[8];
    {
        const size_t wrow = (size_t)(ob + lr) * 256 + lk * 8;
        #pragma unroll
        for (int kk = 0; kk < 8; ++kk) {
            float f[8];
            if (flag) {
                float4 v0 = *(const float4*)((const float*)w + wrow + kk * 32);
                float4 v1 = *(const float4*)((const float*)w + wrow + kk * 32 + 4);
                f[0]=v0.x; f[1]=v0.y; f[2]=v0.z; f[3]=v0.w;
                f[4]=v1.x; f[5]=v1.y; f[6]=v1.z; f[7]=v1.w;
            } else {
                #pragma unroll
                for (int i = 0; i < 8; ++i)
                    f[i] = __bfloat162float(((const bf16*)w)[wrow + kk * 32 + i]);
            }
            #pragma unroll
            for (int i = 0; i < 8; ++i) {
                ushort h = bf16_rne(f[i]);
                wh[kk][i] = (short)h;
                wl[kk][i] = (short)bf16_rne(f[i] - bf16_hi_f(h));
            }
        }
    }

    f32x4 acc[4] = {};
    #pragma unroll
    for (int m = 0; m < 4; ++m) {
        const size_t arow = (size_t)(px0 + m * 16 + lr) * 256 + lk * 8;
        #pragma unroll
        for (int kk = 0; kk < 8; ++kk) {
            s16x8 ah = *(const s16x8*)(Ah + arow + kk * 32);
            s16x8 al = *(const s16x8*)(Al + arow + kk * 32);
            if (OUTHWC) {
                acc[m] = __builtin_amdgcn_mfma_f32_16x16x32_bf16(ah, wh[kk], acc[m], 0, 0, 0);
                acc[m] = __builtin_amdgcn_mfma_f32_16x16x32_bf16(ah, wl[kk], acc[m], 0, 0, 0);
                acc[m] = __builtin_amdgcn_mfma_f32_16x16x32_bf16(al, wh[kk], acc[m], 0, 0, 0);
            } else {
                acc[m] = __builtin_amdgcn_mfma_f32_16x16x32_bf16(wh[kk], ah, acc[m], 0, 0, 0);
                acc[m] = __builtin_amdgcn_mfma_f32_16x16x32_bf16(wl[kk], ah, acc[m], 0, 0, 0);
                acc[m] = __builtin_amdgcn_mfma_f32_16x16x32_bf16(wh[kk], al, acc[m], 0, 0, 0);
            }
        }
    }

    if (OUTHWC) {
        // D: row=px (lk*4+r within m-frag), col=o (lr)
        int o = ob + lr;
        float bv = ldf(bias, o, flag);
        #pragma unroll
        for (int m = 0; m < 4; ++m) {
            #pragma unroll
            for (int r = 0; r < 4; ++r) {
                int px = px0 + m * 16 + lk * 4 + r;
                float v = acc[m][r] + bv;
                if (ACT == 1) v = 1.f / (1.f + __expf(-v));
                out[(size_t)px * COUT + o] = v;
            }
        }
    } else {
        // Swapped operands: D row=o (lk*4+r), col=px (lr). CHW out + residual.
        int img = px0 / HWp;
        int hwb = px0 % HWp;
        #pragma unroll
        for (int r = 0; r < 4; ++r) {
            int o = ob + lk * 4 + r;
            float bv = ldf(bias, o, flag);
            #pragma unroll
            for (int m = 0; m < 4; ++m) {
                int hw = hwb + m * 16 + lr;
                size_t oidx = (size_t)img * IMG + (size_t)o * HWp + hw;
                float v = acc[m][r] + bv;
                if (RES) v += ldf(res, res_base + oidx, flag);
                out[oidx] = v;
            }
        }
    }
}

// ---------------------------------------------------------------------------
// Kernel 5: deformable bilinear sampling + attention sum, channel-last.
// Epilogue emits bf16 hi/lo HWC planes so the final projection runs on MFMA.
// ---------------------------------------------------------------------------
__global__ __launch_bounds__(256) void deform_sample_hwc(
    const float* __restrict__ value,
    const float* __restrict__ offset,
    const float* __restrict__ attn,
    ushort* __restrict__ outh, ushort* __restrict__ outl)
{
    __shared__ int   sIdx[16 * 32 * 4];   // [pix][n*4+p][tap]
    __shared__ float sWt [16 * 32 * 4];

    int tid  = threadIdx.x;
    int pix0 = blockIdx.x * 16;           // chunk-local pixel base

    // ---- phase 1: tap precompute --------------------------------------
    #pragma unroll
    for (int it = 0; it < 2; ++it) {
        int task = it * 256 + tid;        // 512 tasks
        int pix  = task >> 5;             // 0..15
        int np   = task & 31;             // n*4+p
        int gpix = pix0 + pix;
        int hw   = gpix % HWp;
        int i    = hw / Wd;
        int j    = hw % Wd;
        float ox = offset[(size_t)gpix * 64 + np * 2];
        float oy = offset[(size_t)gpix * 64 + np * 2 + 1];
        float a  = attn[(size_t)gpix * 32 + np];
        float ix = (float)j + 0.5f + ox * 47.5f;
        float iy = (float)i + 0.5f + oy * 47.5f;
        float x0 = floorf(ix), y0 = floorf(iy);
        float wx1 = ix - x0, wy1 = iy - y0;
        float wx0 = 1.f - wx1, wy0 = 1.f - wy1;
        int base = task * 4;
        #pragma unroll
        for (int t = 0; t < 4; ++t) {
            float xc = (t & 1) ? x0 + 1.f : x0;
            float yc = (t & 2) ? y0 + 1.f : y0;
            float wt = ((t & 1) ? wx1 : wx0) * ((t & 2) ? wy1 : wy0);
            bool ok  = (xc >= 0.f) & (xc <= 95.f) & (yc >= 0.f) & (yc <= 95.f);
            int xi = min(max((int)xc, 0), 95);
            int yi = min(max((int)yc, 0), 95);
            sIdx[base + t] = yi * Wd + xi;
            sWt [base + t] = ok ? a * wt : 0.f;
        }
    }
    __syncthreads();

    // ---- phase 2: gather + accumulate ---------------------------------
    int c   = tid;                        // 0..255
    int n   = c >> 5;                     // head
    int img = pix0 / HWp;                 // tiles never cross image
    const float* vbase = value + (size_t)img * HWp * 256;

    #pragma unroll 4
    for (int pix = 0; pix < 16; ++pix) {
        int base = (pix * 32 + n * 4) * 4;
        float acc = 0.f;
        #pragma unroll
        for (int p = 0; p < 4; ++p) {
            float4 w4 = *(const float4*)&sWt [base + p * 4];
            int4   i4 = *(const int4*)  &sIdx[base + p * 4];
            acc += w4.x * vbase[(size_t)i4.x * 256 + c];
            acc += w4.y * vbase[(size_t)i4.y * 256 + c];
            acc += w4.z * vbase[(size_t)i4.z * 256 + c];
            acc += w4.w * vbase[(size_t)i4.w * 256 + c];
        }
        ushort h = bf16_rne(acc);
        ushort l = bf16_rne(acc - bf16_hi_f(h));
        size_t o = (size_t)(pix0 + pix) * 256 + c;
        outh[o] = h;
        outl[o] = l;
    }
}

// ---------------------------------------------------------------------------
// Chunked pipeline. Per-image ws: 6 bf16 planes (tOh,tOl,tAh,tAl,Xh,Xl) +
// offset f32 + attn f32 = 31.85 MB. Vf (value, f32 HWC) ALIASES tAh/tAl
// (dead after step 3; identical byte size) -> k=8 fits in ~255 MB.
// Sh/Sl reuse tOh/tOl after step 5. d_out written only by the final kernel.
// ---------------------------------------------------------------------------
extern "C" void kernel_launch(void* const* d_in, const int* in_sizes, int n_in,
                              void* d_out, int out_size, void* d_ws, size_t ws_size,
                              hipStream_t stream)
{
    const void* x        = d_in[0];
    const void* off_dw_w = d_in[1];
    const void* off_dw_b = d_in[2];
    const void* off_bn_g = d_in[3];
    const void* off_bn_b = d_in[4];
    const void* off_bn_m = d_in[5];
    const void* off_bn_v = d_in[6];
    const void* off_pw_w = d_in[7];
    const void* off_pw_b = d_in[8];
    const void* att_dw_w = d_in[9];
    const void* att_dw_b = d_in[10];
    const void* att_bn_g = d_in[11];
    const void* att_bn_b = d_in[12];
    const void* att_bn_m = d_in[13];
    const void* att_bn_v = d_in[14];
    const void* att_pw_w = d_in[15];
    const void* att_pw_b = d_in[16];
    const void* val_w    = d_in[17];
    const void* val_b    = d_in[18];
    const void* out_w    = d_in[19];
    const void* out_b    = d_in[20];

    const size_t perImg = 6 * IMG * 2          // bf16 hi/lo planes
                        + (size_t)HWp * 64 * 4 // offset fp32 HWC
                        + (size_t)HWp * 32 * 4;// attn fp32 HWC
    int k = 1;
    if      (ws_size >= 256 + 8 * perImg) k = 8;
    else if (ws_size >= 256 + 4 * perImg) k = 4;
    else if (ws_size >= 256 + 2 * perImg) k = 2;

    char* ws = (char*)d_ws;
    int*    flag = (int*)ws;
    const size_t kIMG = (size_t)k * IMG;
    ushort* tOh = (ushort*)(ws + 256);         // also Sh after step 5
    ushort* tOl = tOh + kIMG;                  // also Sl
    ushort* tAh = tOl + kIMG;                  // also Vf (f32) after step 3
    ushort* tAl = tAh + kIMG;
    ushort* Xh  = tAl + kIMG;
    ushort* Xl  = Xh  + kIMG;
    float*  Vf  = (float*)tAh;                 // alias: kIMG f32 == 2*kIMG bf16
    float*  OFF = (float*)(Xl + kIMG);
    float*  ATT = OFF + (size_t)k * HWp * 64;

    detect_dtype<<<1, 256, 0, stream>>>(x, flag);

    const int nPx   = k * 144;                 // 64-px tiles
    const int nDef  = k * (HWp / 16);

    for (int b0 = 0; b0 < Bn; b0 += k) {
        size_t xelem = (size_t)b0 * IMG;
        float* outp  = (float*)d_out + xelem;

        // 1. dwconv+BN+ReLU both branches; emit t_off/t_att/x as HWC bf16x2
        dwconv_bn_relu_hwc<<<nPx, 256, 0, stream>>>(
            x, xelem,
            off_dw_w, off_dw_b, off_bn_g, off_bn_b, off_bn_m, off_bn_v,
            att_dw_w, att_dw_b, att_bn_g, att_bn_b, att_bn_m, att_bn_v,
            tOh, tOl, tAh, tAl, Xh, Xl, flag);

        // 2. offset = t_off @ off_pw^T  (64 ch, HWC fp32)
        gemm_mfma<64, 0, false, true><<<nPx, 256, 0, stream>>>(
            tOh, tOl, off_pw_w, off_pw_b, nullptr, 0, OFF, flag);

        // 3. attn = sigmoid(t_att @ att_pw^T)  (32 ch, HWC fp32; 2 waves)
        gemm_mfma<32, 1, false, true><<<nPx, 128, 0, stream>>>(
            tAh, tAl, att_pw_w, att_pw_b, nullptr, 0, ATT, flag);

        // 4. value = x @ val_w^T  (256 ch, HWC fp32) -> Vf (aliases tAh/tAl)
        gemm_mfma<256, 0, false, true><<<nPx * 4, 256, 0, stream>>>(
            Xh, Xl, val_w, val_b, nullptr, 0, Vf, flag);

        // 5. deformable sampling + attention sum -> Sh/Sl (reuse tOh/tOl)
        deform_sample_hwc<<<nDef, 256, 0, stream>>>(Vf, OFF, ATT, tOh, tOl);

        // 6. final projection + bias + residual -> d_out (fp32 CHW)
        gemm_mfma<256, 0, true, false><<<nPx * 4, 256, 0, stream>>>(
            tOh, tOl, out_w, out_b, x, xelem, outp, flag);
    }
}

// Round 5
// 845.414 us; speedup vs baseline: 1.8299x; 1.3298x over previous
//
#include <hip/hip_runtime.h>
#include <hip/hip_bf16.h>

typedef __hip_bfloat16 bf16;

#define HWp 9216
#define Wd  96
#define Hd  96
#define Bn  8
#define Cn  256
#define IMG ((size_t)Cn * HWp)          // 2,359,296 elements per image

typedef __attribute__((ext_vector_type(8))) short        s16x8;
typedef __attribute__((ext_vector_type(8))) ushort       u16x8;
typedef __attribute__((ext_vector_type(8))) unsigned int u32x8;
typedef __attribute__((ext_vector_type(4))) float        f32x4;

// Load element i of a d_in-derived array; flag==1 -> fp32, flag==0 -> bf16.
__device__ __forceinline__ float ldf(const void* p, size_t i, int flag) {
    return flag ? ((const float*)p)[i] : __bfloat162float(((const bf16*)p)[i]);
}
template <int FLAG>
__device__ __forceinline__ float ldT(const void* p, size_t i) {
    return FLAG ? ((const float*)p)[i] : __bfloat162float(((const bf16*)p)[i]);
}

// fp32 -> bf16 bits, round-to-nearest-even (finite data only).
__device__ __forceinline__ ushort bf16_rne(float f) {
    unsigned u = __float_as_uint(f);
    unsigned r = (u + 0x7fffu + ((u >> 16) & 1u)) >> 16;
    return (ushort)r;
}
__device__ __forceinline__ float bf16_hi_f(ushort h) {
    return __uint_as_float((unsigned)h << 16);
}
// pack f into (hi_bf16 << 16) | lo_bf16  (hi + lo ~= f to ~18-bit mantissa)
__device__ __forceinline__ unsigned pack2(float f) {
    ushort h = bf16_rne(f);
    ushort l = bf16_rne(f - bf16_hi_f(h));
    return ((unsigned)h << 16) | l;
}

// ---------------------------------------------------------------------------
// Kernel 0: input dtype probe (fp32 expected; bf16 fallback kept as insurance)
// ---------------------------------------------------------------------------
__global__ void detect_dtype(const void* x, int* flag) {
    __shared__ int cnt;
    if (threadIdx.x == 0) cnt = 0;
    __syncthreads();
    const bf16* p = (const bf16*)x;
    int local = 0;
    #pragma unroll
    for (int k = 0; k < 16; ++k) {
        float w = __bfloat162float(p[threadIdx.x * 16 + k]);
        if (!(fabsf(w) < 1000.f)) local++;
    }
    atomicAdd(&cnt, local);
    __syncthreads();
    if (threadIdx.x == 0) *flag = (cnt > 64) ? 1 : 0;
}

// ---------------------------------------------------------------------------
// Kernel 1 v4: dwconv3x3 + BN + ReLU, both branches.
//  - 64-px strip x 128-ch half per block (grid 2x of v3 -> 9 blocks/CU)
//  - packed u32 (hi|lo bf16) planes: 3 planes instead of 6; per-lane store
//    is 32B contiguous, a 64B line fills in 2 adjacent c8 iterations
//  - XCD-chunked block swizzle: adjacent pixel strips (shared halo rows)
//    stay on the same XCD's L2
// ---------------------------------------------------------------------------
template <int FLAG>
__device__ __forceinline__ void dw_body(
    float (*sPar)[24],
    const void* __restrict__ x, size_t xbase,
    const void* __restrict__ ow, const void* __restrict__ obias,
    const void* __restrict__ og, const void* __restrict__ obeta,
    const void* __restrict__ om, const void* __restrict__ ov,
    const void* __restrict__ aw, const void* __restrict__ abias,
    const void* __restrict__ ag, const void* __restrict__ abeta,
    const void* __restrict__ am, const void* __restrict__ av,
    unsigned* __restrict__ tO, unsigned* __restrict__ tA,
    unsigned* __restrict__ Xp)
{
    const int tid = threadIdx.x;
    const int G   = gridDim.x;                    // multiple of 8
    const int nb  = (blockIdx.x & 7) * (G >> 3) + (blockIdx.x >> 3);
    const int halfTiles = G >> 1;
    const int half = (nb >= halfTiles) ? 1 : 0;   // 128-ch half
    const int pxT  = nb - half * halfTiles;
    const int ch0  = half * 128;

    // ---- stage params for this block's 128 channels
    for (int t = tid; t < 1152; t += 256) {
        int c = t / 9, k = t % 9;
        sPar[c][k]     = ldT<FLAG>(ow, (size_t)(ch0 + c) * 9 + k);
        sPar[c][9 + k] = ldT<FLAG>(aw, (size_t)(ch0 + c) * 9 + k);
    }
    if (tid < 128) {
        int c = ch0 + tid;
        float sco = ldT<FLAG>(og, c) * rsqrtf(ldT<FLAG>(ov, c) + 1e-5f);
        float sca = ldT<FLAG>(ag, c) * rsqrtf(ldT<FLAG>(av, c) + 1e-5f);
        sPar[tid][18] = sco;
        sPar[tid][19] = (ldT<FLAG>(obias, c) - ldT<FLAG>(om, c)) * sco + ldT<FLAG>(obeta, c);
        sPar[tid][20] = sca;
        sPar[tid][21] = (ldT<FLAG>(abias, c) - ldT<FLAG>(am, c)) * sca + ldT<FLAG>(abeta, c);
    }
    __syncthreads();

    const int pl  = tid & 63;                 // pixel within strip
    const int cg  = tid >> 6;                 // 32-ch group (wave-uniform)
    const int gpx = pxT * 64 + pl;            // 9216 % 64 == 0: no image cross
    const int img = gpx / HWp;
    const int hw  = gpx % HWp;
    const int i   = hw / Wd, j = hw % Wd;

    int  idxk[9];
    bool mk[9];
    #pragma unroll
    for (int k = 0; k < 9; ++k) {
        int di = k / 3 - 1, dj = k % 3 - 1;
        int ii = i + di, jj = j + dj;
        mk[k]   = (ii >= 0) & (ii < Hd) & (jj >= 0) & (jj < Wd);
        idxk[k] = min(max(ii, 0), Hd - 1) * Wd + min(max(jj, 0), Wd - 1);
    }

    const size_t pbase = xbase + (size_t)img * IMG + (size_t)(ch0 + cg * 32) * HWp;
    const size_t obase = (size_t)gpx * 256 + ch0 + cg * 32;   // u32 index

    #pragma unroll 1
    for (int c8 = 0; c8 < 4; ++c8) {
        u32x8 vo, va, vx;
        #pragma unroll
        for (int cc = 0; cc < 8; ++cc) {
            int    cl = cg * 32 + c8 * 8 + cc;       // local channel
            size_t b  = pbase + (size_t)(c8 * 8 + cc) * HWp;
            float xv[9];
            #pragma unroll
            for (int k = 0; k < 9; ++k) xv[k] = ldT<FLAG>(x, b + idxk[k]);
            float so = 0.f, sa = 0.f;
            #pragma unroll
            for (int k = 0; k < 9; ++k) {
                float xm = mk[k] ? xv[k] : 0.f;      // cndmask, no branch
                so = fmaf(xm, sPar[cl][k],     so);
                sa = fmaf(xm, sPar[cl][9 + k], sa);
            }
            float xc = xv[4];                        // center tap, always valid
            float to = fmaxf(fmaf(so, sPar[cl][18], sPar[cl][19]), 0.f);
            float ta = fmaxf(fmaf(sa, sPar[cl][20], sPar[cl][21]), 0.f);
            vo[cc] = pack2(to);
            va[cc] = pack2(ta);
            vx[cc] = pack2(xc);
        }
        size_t o = obase + c8 * 8;
        *(u32x8*)(tO + o) = vo;
        *(u32x8*)(tA + o) = va;
        *(u32x8*)(Xp + o) = vx;
    }
}

__global__ __launch_bounds__(256) void dwconv_bn_relu_hwc(
    const void* __restrict__ x, size_t xbase,
    const void* __restrict__ ow, const void* __restrict__ obias,
    const void* __restrict__ og, const void* __restrict__ obeta,
    const void* __restrict__ om, const void* __restrict__ ov,
    const void* __restrict__ aw, const void* __restrict__ abias,
    const void* __restrict__ ag, const void* __restrict__ abeta,
    const void* __restrict__ am, const void* __restrict__ av,
    unsigned* __restrict__ tO, unsigned* __restrict__ tA,
    unsigned* __restrict__ Xp, const int* __restrict__ flagp)
{
    __shared__ float sPar[128][24];
    if (*flagp)
        dw_body<1>(sPar, x, xbase, ow, obias, og, obeta, om, ov,
                   aw, abias, ag, abeta, am, av, tO, tA, Xp);
    else
        dw_body<0>(sPar, x, xbase, ow, obias, og, obeta, om, ov,
                   aw, abias, ag, abeta, am, av, tO, tA, Xp);
}

// ---------------------------------------------------------------------------
// MFMA 1x1-conv GEMM, K=256, bf16x2 split (hi/lo; 3 MFMAs/k-tile -> ~18-bit
// effective input mantissa). A: packed u32 plane [px][256] ((hi<<16)|lo).
// W: d_in fp32/bf16 [COUT][256]. Tile 64 px x 64 out; wave owns 16 outs.
// No LDS, no barriers. COUT=32 launched with 128 threads (2 waves).
// NTO==4: XCD-aware swizzle so the 4 o-tiles sharing one A px-tile land on
// the SAME XCD (round-robin heuristic) -> A L2-reused.
// A-frag and B-frag lane layouts are mutual transposes -> swapping mfma
// operand order yields D^T: used for the CHW-output (+residual) final conv.
// ---------------------------------------------------------------------------
template <int COUT, int ACT, bool RES, bool OUTHWC>
__global__ __launch_bounds__(256) void gemm_mfma(
    const unsigned* __restrict__ Ap,
    const void* __restrict__ w, const void* __restrict__ bias,
    const void* __restrict__ res, size_t res_base,
    float* __restrict__ out, const int* __restrict__ flagp)
{
    constexpr int NTO = (COUT + 63) / 64;
    const int flag = *flagp;
    const int lane = threadIdx.x & 63;
    const int wv   = threadIdx.x >> 6;

    int pt, ot;
    if constexpr (NTO == 4) {
        int b = blockIdx.x, g = b >> 3, xcd = b & 7;
        ot = g & 3;
        pt = xcd + 8 * (g >> 2);
    } else {
        ot = 0;
        pt = blockIdx.x;
    }
    const int px0 = pt * 64;
    const int ob  = ot * 64 + wv * 16;
    if (ob >= COUT) return;

    const int lr = lane & 15;
    const int lk = lane >> 4;

    // ---- weight fragments, hi/lo
    s16x8 wh[8], wl[8];
    {
        const size_t wrow = (size_t)(ob + lr) * 256 + lk * 8;
        #pragma unroll
        for (int kk = 0; kk < 8; ++kk) {
            float f[8];
            if (flag) {
                float4 v0 = *(const float4*)((const float*)w + wrow + kk * 32);
                float4 v1 = *(const float4*)((const float*)w + wrow + kk * 32 + 4);
                f[0]=v0.x; f[1]=v0.y; f[2]=v0.z; f[3]=v0.w;
                f[4]=v1.x; f[5]=v1.y; f[6]=v1.z; f[7]=v1.w;
            } else {
                #pragma unroll
                for (int i = 0; i < 8; ++i)
                    f[i] = __bfloat162float(((const bf16*)w)[wrow + kk * 32 + i]);
            }
            #pragma unroll
            for (int i = 0; i < 8; ++i) {
                ushort h = bf16_rne(f[i]);
                wh[kk][i] = (short)h;
                wl[kk][i] = (short)bf16_rne(f[i] - bf16_hi_f(h));
            }
        }
    }

    f32x4 acc[4] = {};
    #pragma unroll
    for (int m = 0; m < 4; ++m) {
        const size_t arow = (size_t)(px0 + m * 16 + lr) * 256 + lk * 8;
        #pragma unroll
        for (int kk = 0; kk < 8; ++kk) {
            u32x8 av = *(const u32x8*)(Ap + arow + kk * 32);
            s16x8 ah, al;
            #pragma unroll
            for (int i = 0; i < 8; ++i) {
                ah[i] = (short)(av[i] >> 16);
                al[i] = (short)(av[i] & 0xffffu);
            }
            if (OUTHWC) {
                acc[m] = __builtin_amdgcn_mfma_f32_16x16x32_bf16(ah, wh[kk], acc[m], 0, 0, 0);
                acc[m] = __builtin_amdgcn_mfma_f32_16x16x32_bf16(ah, wl[kk], acc[m], 0, 0, 0);
                acc[m] = __builtin_amdgcn_mfma_f32_16x16x32_bf16(al, wh[kk], acc[m], 0, 0, 0);
            } else {
                acc[m] = __builtin_amdgcn_mfma_f32_16x16x32_bf16(wh[kk], ah, acc[m], 0, 0, 0);
                acc[m] = __builtin_amdgcn_mfma_f32_16x16x32_bf16(wl[kk], ah, acc[m], 0, 0, 0);
                acc[m] = __builtin_amdgcn_mfma_f32_16x16x32_bf16(wh[kk], al, acc[m], 0, 0, 0);
            }
        }
    }

    if (OUTHWC) {
        // D: row=px (lk*4+r within m-frag), col=o (lr)
        int o = ob + lr;
        float bv = ldf(bias, o, flag);
        #pragma unroll
        for (int m = 0; m < 4; ++m) {
            #pragma unroll
            for (int r = 0; r < 4; ++r) {
                int px = px0 + m * 16 + lk * 4 + r;
                float v = acc[m][r] + bv;
                if (ACT == 1) v = 1.f / (1.f + __expf(-v));
                out[(size_t)px * COUT + o] = v;
            }
        }
    } else {
        // Swapped operands: D row=o (lk*4+r), col=px (lr). CHW out + residual.
        int img = px0 / HWp;
        int hwb = px0 % HWp;
        #pragma unroll
        for (int r = 0; r < 4; ++r) {
            int o = ob + lk * 4 + r;
            float bv = ldf(bias, o, flag);
            #pragma unroll
            for (int m = 0; m < 4; ++m) {
                int hw = hwb + m * 16 + lr;
                size_t oidx = (size_t)img * IMG + (size_t)o * HWp + hw;
                float v = acc[m][r] + bv;
                if (RES) v += ldf(res, res_base + oidx, flag);
                out[oidx] = v;
            }
        }
    }
}

// ---------------------------------------------------------------------------
// Kernel 5 v4: deformable bilinear sampling + attention sum, channel-last.
//  - XCD-chunked block swizzle: each XCD owns one contiguous pixel range
//    (one image at k=8) -> tap band (~2 MB) stays in its 4 MB L2
//  - float4-vectorized gather: wave reads 1 KB contiguous per tap
//  - epilogue emits packed u32 (hi|lo bf16) plane for the MFMA projection
// ---------------------------------------------------------------------------
__global__ __launch_bounds__(256) void deform_sample_hwc(
    const float* __restrict__ value,
    const float* __restrict__ offset,
    const float* __restrict__ attn,
    unsigned* __restrict__ outp)
{
    __shared__ int   sIdx[16 * 32 * 4];   // [pix][n*4+p][tap]
    __shared__ float sWt [16 * 32 * 4];

    int tid  = threadIdx.x;
    const int G  = gridDim.x;                          // multiple of 8
    const int nb = (blockIdx.x & 7) * (G >> 3) + (blockIdx.x >> 3);
    int pix0 = nb * 16;                                // chunk-local pixel base

    // ---- phase 1: tap precompute --------------------------------------
    #pragma unroll
    for (int it = 0; it < 2; ++it) {
        int task = it * 256 + tid;        // 512 tasks
        int pix  = task >> 5;             // 0..15
        int np   = task & 31;             // n*4+p
        int gpix = pix0 + pix;
        int hw   = gpix % HWp;
        int i    = hw / Wd;
        int j    = hw % Wd;
        float ox = offset[(size_t)gpix * 64 + np * 2];
        float oy = offset[(size_t)gpix * 64 + np * 2 + 1];
        float a  = attn[(size_t)gpix * 32 + np];
        float ix = (float)j + 0.5f + ox * 47.5f;
        float iy = (float)i + 0.5f + oy * 47.5f;
        float x0 = floorf(ix), y0 = floorf(iy);
        float wx1 = ix - x0, wy1 = iy - y0;
        float wx0 = 1.f - wx1, wy0 = 1.f - wy1;
        int base = task * 4;
        #pragma unroll
        for (int t = 0; t < 4; ++t) {
            float xc = (t & 1) ? x0 + 1.f : x0;
            float yc = (t & 2) ? y0 + 1.f : y0;
            float wt = ((t & 1) ? wx1 : wx0) * ((t & 2) ? wy1 : wy0);
            bool ok  = (xc >= 0.f) & (xc <= 95.f) & (yc >= 0.f) & (yc <= 95.f);
            int xi = min(max((int)xc, 0), 95);
            int yi = min(max((int)yc, 0), 95);
            sIdx[base + t] = yi * Wd + xi;
            sWt [base + t] = ok ? a * wt : 0.f;
        }
    }
    __syncthreads();

    // ---- phase 2: vectorized gather + accumulate ----------------------
    const int lane = tid & 63;
    const int wvv  = tid >> 6;
    const int c4   = lane * 4;            // 4 consecutive channels
    const int n    = lane >> 3;           // head = c4>>5
    const int img  = pix0 / HWp;          // tiles never cross image
    const float* vbase = value + (size_t)img * HWp * 256;

    #pragma unroll
    for (int pi = 0; pi < 4; ++pi) {
        int pix  = wvv * 4 + pi;
        int base = (pix * 32 + n * 4) * 4;
        f32x4 acc = {};
        #pragma unroll
        for (int p = 0; p < 4; ++p) {
            #pragma unroll
            for (int t = 0; t < 4; ++t) {
                float wt = sWt [base + p * 4 + t];
                int   ix = sIdx[base + p * 4 + t];
                float4 v = *(const float4*)&vbase[(size_t)ix * 256 + c4];
                acc[0] = fmaf(wt, v.x, acc[0]);
                acc[1] = fmaf(wt, v.y, acc[1]);
                acc[2] = fmaf(wt, v.z, acc[2]);
                acc[3] = fmaf(wt, v.w, acc[3]);
            }
        }
        uint4 o;
        o.x = pack2(acc[0]); o.y = pack2(acc[1]);
        o.z = pack2(acc[2]); o.w = pack2(acc[3]);
        *(uint4*)&outp[(size_t)(pix0 + pix) * 256 + c4] = o;
    }
}

// ---------------------------------------------------------------------------
// Chunked pipeline. Per-image ws: 3 packed u32 planes (tO,tA,Xp) +
// offset f32 + attn f32 = 31.85 MB -> k=8 fits in ~255 MB.
// Vf (value, f32 HWC) aliases tA (dead after step 3); S (sampled, packed)
// reuses tO (dead after step 2). d_out written only by the final kernel.
// ---------------------------------------------------------------------------
extern "C" void kernel_launch(void* const* d_in, const int* in_sizes, int n_in,
                              void* d_out, int out_size, void* d_ws, size_t ws_size,
                              hipStream_t stream)
{
    const void* x        = d_in[0];
    const void* off_dw_w = d_in[1];
    const void* off_dw_b = d_in[2];
    const void* off_bn_g = d_in[3];
    const void* off_bn_b = d_in[4];
    const void* off_bn_m = d_in[5];
    const void* off_bn_v = d_in[6];
    const void* off_pw_w = d_in[7];
    const void* off_pw_b = d_in[8];
    const void* att_dw_w = d_in[9];
    const void* att_dw_b = d_in[10];
    const void* att_bn_g = d_in[11];
    const void* att_bn_b = d_in[12];
    const void* att_bn_m = d_in[13];
    const void* att_bn_v = d_in[14];
    const void* att_pw_w = d_in[15];
    const void* att_pw_b = d_in[16];
    const void* val_w    = d_in[17];
    const void* val_b    = d_in[18];
    const void* out_w    = d_in[19];
    const void* out_b    = d_in[20];

    const size_t perImg = 3 * IMG * 4          // packed u32 planes
                        + (size_t)HWp * 64 * 4 // offset fp32 HWC
                        + (size_t)HWp * 32 * 4;// attn fp32 HWC
    int k = 1;
    if      (ws_size >= 256 + 8 * perImg) k = 8;
    else if (ws_size >= 256 + 4 * perImg) k = 4;
    else if (ws_size >= 256 + 2 * perImg) k = 2;

    char* ws = (char*)d_ws;
    int*      flag = (int*)ws;
    const size_t kIMG = (size_t)k * IMG;
    unsigned* tO  = (unsigned*)(ws + 256);     // also S (sampled) after step 2
    unsigned* tA  = tO + kIMG;                 // also Vf (f32) after step 3
    unsigned* Xp  = tA + kIMG;
    float*    Vf  = (float*)tA;
    float*    OFF = (float*)(Xp + kIMG);
    float*    ATT = OFF + (size_t)k * HWp * 64;

    detect_dtype<<<1, 256, 0, stream>>>(x, flag);

    const int nPx  = k * 144;                  // 64-px GEMM tiles
    const int nDw  = k * 288;                  // 64-px x 128-ch dwconv tiles
    const int nDef = k * (HWp / 16);

    for (int b0 = 0; b0 < Bn; b0 += k) {
        size_t xelem = (size_t)b0 * IMG;
        float* outp  = (float*)d_out + xelem;

        // 1. dwconv+BN+ReLU both branches; emit t_off/t_att/x packed HWC
        dwconv_bn_relu_hwc<<<nDw, 256, 0, stream>>>(
            x, xelem,
            off_dw_w, off_dw_b, off_bn_g, off_bn_b, off_bn_m, off_bn_v,
            att_dw_w, att_dw_b, att_bn_g, att_bn_b, att_bn_m, att_bn_v,
            tO, tA, Xp, flag);

        // 2. offset = t_off @ off_pw^T  (64 ch, HWC fp32)
        gemm_mfma<64, 0, false, true><<<nPx, 256, 0, stream>>>(
            tO, off_pw_w, off_pw_b, nullptr, 0, OFF, flag);

        // 3. attn = sigmoid(t_att @ att_pw^T)  (32 ch, HWC fp32; 2 waves)
        gemm_mfma<32, 1, false, true><<<nPx, 128, 0, stream>>>(
            tA, att_pw_w, att_pw_b, nullptr, 0, ATT, flag);

        // 4. value = x @ val_w^T  (256 ch, HWC fp32) -> Vf (aliases tA)
        gemm_mfma<256, 0, false, true><<<nPx * 4, 256, 0, stream>>>(
            Xp, val_w, val_b, nullptr, 0, Vf, flag);

        // 5. deformable sampling + attention sum -> S (reuses tO)
        deform_sample_hwc<<<nDef, 256, 0, stream>>>(Vf, OFF, ATT, tO);

        // 6. final projection + bias + residual -> d_out (fp32 CHW)
        gemm_mfma<256, 0, true, false><<<nPx * 4, 256, 0, stream>>>(
            tO, out_w, out_b, x, xelem, outp, flag);
    }
}

// Round 6
// 778.243 us; speedup vs baseline: 1.9879x; 1.0863x over previous
//
#include <hip/hip_runtime.h>
#include <hip/hip_bf16.h>

typedef __hip_bfloat16 bf16;

#define HWp 9216
#define Wd  96
#define Hd  96
#define Bn  8
#define Cn  256
#define IMG ((size_t)Cn * HWp)          // 2,359,296 elements per image

typedef __attribute__((ext_vector_type(8))) short        s16x8;
typedef __attribute__((ext_vector_type(8))) ushort       u16x8;
typedef __attribute__((ext_vector_type(8))) unsigned int u32x8;
typedef __attribute__((ext_vector_type(4))) float        f32x4;

// Load element i of a d_in-derived array; flag==1 -> fp32, flag==0 -> bf16.
__device__ __forceinline__ float ldf(const void* p, size_t i, int flag) {
    return flag ? ((const float*)p)[i] : __bfloat162float(((const bf16*)p)[i]);
}
template <int FLAG>
__device__ __forceinline__ float ldT(const void* p, size_t i) {
    return FLAG ? ((const float*)p)[i] : __bfloat162float(((const bf16*)p)[i]);
}

// fp32 -> bf16 bits, round-to-nearest-even (finite data only).
__device__ __forceinline__ ushort bf16_rne(float f) {
    unsigned u = __float_as_uint(f);
    unsigned r = (u + 0x7fffu + ((u >> 16) & 1u)) >> 16;
    return (ushort)r;
}
__device__ __forceinline__ float bf16_hi_f(ushort h) {
    return __uint_as_float((unsigned)h << 16);
}
// pack f into (hi_bf16 << 16) | lo_bf16, RNE both halves (~18-bit mantissa)
__device__ __forceinline__ unsigned pack2(float f) {
    ushort h = bf16_rne(f);
    ushort l = bf16_rne(f - bf16_hi_f(h));
    return ((unsigned)h << 16) | l;
}
// cheap pack: truncate hi, truncate residual lo (~14-bit mantissa, 5 VALU)
__device__ __forceinline__ unsigned packT(float f) {
    unsigned u  = __float_as_uint(f);
    unsigned hi = u & 0xffff0000u;
    float    r  = f - __uint_as_float(hi);
    return hi | (__float_as_uint(r) >> 16);
}

// ---------------------------------------------------------------------------
// Kernel 0: input dtype probe (fp32 expected; bf16 fallback kept as insurance)
// ---------------------------------------------------------------------------
__global__ void detect_dtype(const void* x, int* flag) {
    __shared__ int cnt;
    if (threadIdx.x == 0) cnt = 0;
    __syncthreads();
    const bf16* p = (const bf16*)x;
    int local = 0;
    #pragma unroll
    for (int k = 0; k < 16; ++k) {
        float w = __bfloat162float(p[threadIdx.x * 16 + k]);
        if (!(fabsf(w) < 1000.f)) local++;
    }
    atomicAdd(&cnt, local);
    __syncthreads();
    if (threadIdx.x == 0) *flag = (cnt > 64) ? 1 : 0;
}

// ---------------------------------------------------------------------------
// Kernel 1 v5: dwconv3x3 + BN + ReLU, both branches.
// Block = one 8-px group x 256 channels (thread = channel). NO LDS:
//  - 18 conv weights + 4 BN consts per thread in REGISTERS (kills the v4
//    ds_read/lgkmcnt stall that pinned VALUBusy at 14.5%)
//  - pixel geometry wave-uniform -> edge masks are scalar branches folded
//    into the weight registers / 2 window slots
//  - taps: 3 rows x 16-col windows via 4 aligned float4 each (clamped col
//    bases, statically masked edge slots; never OOB)
//  - stores: lane=channel -> 256B contiguous per instruction, full packed
//    HWC rows per block (32B sectors -> no write-allocate, per round-5)
// ---------------------------------------------------------------------------
template <int FLAG>
__device__ __forceinline__ void dw_body(
    const void* __restrict__ x, size_t xbase,
    const void* __restrict__ ow, const void* __restrict__ obias,
    const void* __restrict__ og, const void* __restrict__ obeta,
    const void* __restrict__ om, const void* __restrict__ ov,
    const void* __restrict__ aw, const void* __restrict__ abias,
    const void* __restrict__ ag, const void* __restrict__ abeta,
    const void* __restrict__ am, const void* __restrict__ av,
    unsigned* __restrict__ tO, unsigned* __restrict__ tA,
    unsigned* __restrict__ Xp)
{
    const int G   = gridDim.x;                       // k*1152, multiple of 8
    const int nb  = (blockIdx.x & 7) * (G >> 3) + (blockIdx.x >> 3);
    const int c   = threadIdx.x;                     // channel 0..255
    const int img = nb / 1152;
    const int gl  = nb % 1152;
    const int i   = gl / 12;                         // row (wave-uniform)
    const int j0  = (gl % 12) * 8;                   // col base (wave-uniform)

    // ---- per-channel params in registers
    float wo[9], wa[9];
    #pragma unroll
    for (int k = 0; k < 9; ++k) {
        wo[k] = ldT<FLAG>(ow, (size_t)c * 9 + k);
        wa[k] = ldT<FLAG>(aw, (size_t)c * 9 + k);
    }
    float sco = ldT<FLAG>(og, c) * rsqrtf(ldT<FLAG>(ov, c) + 1e-5f);
    float sho = (ldT<FLAG>(obias, c) - ldT<FLAG>(om, c)) * sco + ldT<FLAG>(obeta, c);
    float sca = ldT<FLAG>(ag, c) * rsqrtf(ldT<FLAG>(av, c) + 1e-5f);
    float sha = (ldT<FLAG>(abias, c) - ldT<FLAG>(am, c)) * sca + ldT<FLAG>(abeta, c);

    // row-edge masks folded into weights (wave-uniform branches)
    if (i == 0)      { wo[0]=wo[1]=wo[2]=0.f; wa[0]=wa[1]=wa[2]=0.f; }
    if (i == Hd - 1) { wo[6]=wo[7]=wo[8]=0.f; wa[6]=wa[7]=wa[8]=0.f; }

    // ---- load 3 rows x 16-col windows; w3[r][idx] = col (j0-4+idx)
    const size_t plane = xbase + (size_t)img * IMG + (size_t)c * HWp;
    const int c00 = (j0 == 0)  ? 0  : j0 - 4;        // wave-uniform
    const int c03 = (j0 == 88) ? 92 : j0 + 8;
    float w3[3][16];
    #pragma unroll
    for (int r3 = 0; r3 < 3; ++r3) {
        int rr = min(max(i - 1 + r3, 0), Hd - 1);
        size_t rb = plane + (size_t)rr * Wd;
        if (FLAG) {
            *(float4*)&w3[r3][0]  = *(const float4*)((const float*)x + rb + c00);
            *(float4*)&w3[r3][4]  = *(const float4*)((const float*)x + rb + j0);
            *(float4*)&w3[r3][8]  = *(const float4*)((const float*)x + rb + j0 + 4);
            *(float4*)&w3[r3][12] = *(const float4*)((const float*)x + rb + c03);
        } else {
            #pragma unroll
            for (int t = 0; t < 4; ++t) {
                w3[r3][t]      = ldT<FLAG>(x, rb + c00 + t);
                w3[r3][4 + t]  = ldT<FLAG>(x, rb + j0 + t);
                w3[r3][8 + t]  = ldT<FLAG>(x, rb + j0 + 4 + t);
                w3[r3][12 + t] = ldT<FLAG>(x, rb + c03 + t);
            }
        }
    }
    // col-edge masks: idx3 is col j0-1 (only used by p=0,dj=-1);
    // idx12 is col j0+8 (only used by p=7,dj=+1)
    if (j0 == 0)  { w3[0][3]  = 0.f; w3[1][3]  = 0.f; w3[2][3]  = 0.f; }
    if (j0 == 88) { w3[0][12] = 0.f; w3[1][12] = 0.f; w3[2][12] = 0.f; }

    // ---- compute 8 px, pack
    unsigned ro[8], ra[8], rx[8];
    #pragma unroll
    for (int p = 0; p < 8; ++p) {
        float so = 0.f, sa = 0.f;
        #pragma unroll
        for (int r3 = 0; r3 < 3; ++r3) {
            #pragma unroll
            for (int dj = 0; dj < 3; ++dj) {
                float xv = w3[r3][3 + p + dj];       // static idx 3..12
                so = fmaf(xv, wo[r3 * 3 + dj], so);
                sa = fmaf(xv, wa[r3 * 3 + dj], sa);
            }
        }
        float to = fmaxf(fmaf(so, sco, sho), 0.f);
        float ta = fmaxf(fmaf(sa, sca, sha), 0.f);
        ro[p] = packT(to);
        ra[p] = packT(ta);
        rx[p] = packT(w3[1][4 + p]);                 // center tap = x itself
    }

    // ---- stores: lane=c -> 256B contiguous per inst, full rows per block
    const size_t ob = (size_t)nb * 8 * 256 + c;
    #pragma unroll
    for (int p = 0; p < 8; ++p) {
        tO[ob + p * 256] = ro[p];
        tA[ob + p * 256] = ra[p];
        Xp[ob + p * 256] = rx[p];
    }
}

__global__ __launch_bounds__(256) void dwconv_bn_relu_hwc(
    const void* __restrict__ x, size_t xbase,
    const void* __restrict__ ow, const void* __restrict__ obias,
    const void* __restrict__ og, const void* __restrict__ obeta,
    const void* __restrict__ om, const void* __restrict__ ov,
    const void* __restrict__ aw, const void* __restrict__ abias,
    const void* __restrict__ ag, const void* __restrict__ abeta,
    const void* __restrict__ am, const void* __restrict__ av,
    unsigned* __restrict__ tO, unsigned* __restrict__ tA,
    unsigned* __restrict__ Xp, const int* __restrict__ flagp)
{
    if (*flagp)
        dw_body<1>(x, xbase, ow, obias, og, obeta, om, ov,
                   aw, abias, ag, abeta, am, av, tO, tA, Xp);
    else
        dw_body<0>(x, xbase, ow, obias, og, obeta, om, ov,
                   aw, abias, ag, abeta, am, av, tO, tA, Xp);
}

// ---------------------------------------------------------------------------
// MFMA 1x1-conv GEMM, K=256, bf16x2 split (hi/lo; 3 MFMAs/k-tile).
// A: packed u32 plane [px][256] ((hi<<16)|lo). W: d_in fp32/bf16 [COUT][256].
// Tile 64 px x 64 out; wave owns 16 outs. No LDS, no barriers.
// NTO==4: XCD-aware swizzle so the 4 o-tiles sharing one A px-tile land on
// the SAME XCD. A-frag and B-frag lane layouts are mutual transposes ->
// swapping mfma operand order yields D^T (CHW-output final conv).
// ---------------------------------------------------------------------------
template <int COUT, int ACT, bool RES, bool OUTHWC>
__global__ __launch_bounds__(256) void gemm_mfma(
    const unsigned* __restrict__ Ap,
    const void* __restrict__ w, const void* __restrict__ bias,
    const void* __restrict__ res, size_t res_base,
    float* __restrict__ out, const int* __restrict__ flagp)
{
    constexpr int NTO = (COUT + 63) / 64;
    const int flag = *flagp;
    const int lane = threadIdx.x & 63;
    const int wv   = threadIdx.x >> 6;

    int pt, ot;
    if constexpr (NTO == 4) {
        int b = blockIdx.x, g = b >> 3, xcd = b & 7;
        ot = g & 3;
        pt = xcd + 8 * (g >> 2);
    } else {
        ot = 0;
        pt = blockIdx.x;
    }
    const int px0 = pt * 64;
    const int ob  = ot * 64 + wv * 16;
    if (ob >= COUT) return;

    const int lr = lane & 15;
    const int lk = lane >> 4;

    // ---- weight fragments, hi/lo
    s16x8 wh[8], wl[8];
    {
        const size_t wrow = (size_t)(ob + lr) * 256 + lk * 8;
        #pragma unroll
        for (int kk = 0; kk < 8; ++kk) {
            float f[8];
            if (flag) {
                float4 v0 = *(const float4*)((const float*)w + wrow + kk * 32);
                float4 v1 = *(const float4*)((const float*)w + wrow + kk * 32 + 4);
                f[0]=v0.x; f[1]=v0.y; f[2]=v0.z; f[3]=v0.w;
                f[4]=v1.x; f[5]=v1.y; f[6]=v1.z; f[7]=v1.w;
            } else {
                #pragma unroll
                for (int i = 0; i < 8; ++i)
                    f[i] = __bfloat162float(((const bf16*)w)[wrow + kk * 32 + i]);
            }
            #pragma unroll
            for (int i = 0; i < 8; ++i) {
                ushort h = bf16_rne(f[i]);
                wh[kk][i] = (short)h;
                wl[kk][i] = (short)bf16_rne(f[i] - bf16_hi_f(h));
            }
        }
    }

    f32x4 acc[4] = {};
    #pragma unroll
    for (int m = 0; m < 4; ++m) {
        const size_t arow = (size_t)(px0 + m * 16 + lr) * 256 + lk * 8;
        #pragma unroll
        for (int kk = 0; kk < 8; ++kk) {
            u32x8 av = *(const u32x8*)(Ap + arow + kk * 32);
            s16x8 ah, al;
            #pragma unroll
            for (int i = 0; i < 8; ++i) {
                ah[i] = (short)(av[i] >> 16);
                al[i] = (short)(av[i] & 0xffffu);
            }
            if (OUTHWC) {
                acc[m] = __builtin_amdgcn_mfma_f32_16x16x32_bf16(ah, wh[kk], acc[m], 0, 0, 0);
                acc[m] = __builtin_amdgcn_mfma_f32_16x16x32_bf16(ah, wl[kk], acc[m], 0, 0, 0);
                acc[m] = __builtin_amdgcn_mfma_f32_16x16x32_bf16(al, wh[kk], acc[m], 0, 0, 0);
            } else {
                acc[m] = __builtin_amdgcn_mfma_f32_16x16x32_bf16(wh[kk], ah, acc[m], 0, 0, 0);
                acc[m] = __builtin_amdgcn_mfma_f32_16x16x32_bf16(wl[kk], ah, acc[m], 0, 0, 0);
                acc[m] = __builtin_amdgcn_mfma_f32_16x16x32_bf16(wh[kk], al, acc[m], 0, 0, 0);
            }
        }
    }

    if (OUTHWC) {
        // D: row=px (lk*4+r within m-frag), col=o (lr)
        int o = ob + lr;
        float bv = ldf(bias, o, flag);
        #pragma unroll
        for (int m = 0; m < 4; ++m) {
            #pragma unroll
            for (int r = 0; r < 4; ++r) {
                int px = px0 + m * 16 + lk * 4 + r;
                float v = acc[m][r] + bv;
                if (ACT == 1) v = 1.f / (1.f + __expf(-v));
                out[(size_t)px * COUT + o] = v;
            }
        }
    } else {
        // Swapped operands: D row=o (lk*4+r), col=px (lr). CHW out + residual.
        int img = px0 / HWp;
        int hwb = px0 % HWp;
        #pragma unroll
        for (int r = 0; r < 4; ++r) {
            int o = ob + lk * 4 + r;
            float bv = ldf(bias, o, flag);
            #pragma unroll
            for (int m = 0; m < 4; ++m) {
                int hw = hwb + m * 16 + lr;
                size_t oidx = (size_t)img * IMG + (size_t)o * HWp + hw;
                float v = acc[m][r] + bv;
                if (RES) v += ldf(res, res_base + oidx, flag);
                out[oidx] = v;
            }
        }
    }
}

// ---------------------------------------------------------------------------
// Kernel 5 v4: deformable bilinear sampling + attention sum, channel-last.
//  - XCD-chunked block swizzle (value tap band stays in one XCD's L2)
//  - float4-vectorized gather; packed u32 epilogue for the MFMA projection
// ---------------------------------------------------------------------------
__global__ __launch_bounds__(256) void deform_sample_hwc(
    const float* __restrict__ value,
    const float* __restrict__ offset,
    const float* __restrict__ attn,
    unsigned* __restrict__ outp)
{
    __shared__ int   sIdx[16 * 32 * 4];   // [pix][n*4+p][tap]
    __shared__ float sWt [16 * 32 * 4];

    int tid  = threadIdx.x;
    const int G  = gridDim.x;                          // multiple of 8
    const int nb = (blockIdx.x & 7) * (G >> 3) + (blockIdx.x >> 3);
    int pix0 = nb * 16;                                // chunk-local pixel base

    // ---- phase 1: tap precompute --------------------------------------
    #pragma unroll
    for (int it = 0; it < 2; ++it) {
        int task = it * 256 + tid;        // 512 tasks
        int pix  = task >> 5;             // 0..15
        int np   = task & 31;             // n*4+p
        int gpix = pix0 + pix;
        int hw   = gpix % HWp;
        int i    = hw / Wd;
        int j    = hw % Wd;
        float ox = offset[(size_t)gpix * 64 + np * 2];
        float oy = offset[(size_t)gpix * 64 + np * 2 + 1];
        float a  = attn[(size_t)gpix * 32 + np];
        float ix = (float)j + 0.5f + ox * 47.5f;
        float iy = (float)i + 0.5f + oy * 47.5f;
        float x0 = floorf(ix), y0 = floorf(iy);
        float wx1 = ix - x0, wy1 = iy - y0;
        float wx0 = 1.f - wx1, wy0 = 1.f - wy1;
        int base = task * 4;
        #pragma unroll
        for (int t = 0; t < 4; ++t) {
            float xc = (t & 1) ? x0 + 1.f : x0;
            float yc = (t & 2) ? y0 + 1.f : y0;
            float wt = ((t & 1) ? wx1 : wx0) * ((t & 2) ? wy1 : wy0);
            bool ok  = (xc >= 0.f) & (xc <= 95.f) & (yc >= 0.f) & (yc <= 95.f);
            int xi = min(max((int)xc, 0), 95);
            int yi = min(max((int)yc, 0), 95);
            sIdx[base + t] = yi * Wd + xi;
            sWt [base + t] = ok ? a * wt : 0.f;
        }
    }
    __syncthreads();

    // ---- phase 2: vectorized gather + accumulate ----------------------
    const int lane = tid & 63;
    const int wvv  = tid >> 6;
    const int c4   = lane * 4;            // 4 consecutive channels
    const int n    = lane >> 3;           // head = c4>>5
    const int img  = pix0 / HWp;          // tiles never cross image
    const float* vbase = value + (size_t)img * HWp * 256;

    #pragma unroll
    for (int pi = 0; pi < 4; ++pi) {
        int pix  = wvv * 4 + pi;
        int base = (pix * 32 + n * 4) * 4;
        f32x4 acc = {};
        #pragma unroll
        for (int p = 0; p < 4; ++p) {
            #pragma unroll
            for (int t = 0; t < 4; ++t) {
                float wt = sWt [base + p * 4 + t];
                int   ix = sIdx[base + p * 4 + t];
                float4 v = *(const float4*)&vbase[(size_t)ix * 256 + c4];
                acc[0] = fmaf(wt, v.x, acc[0]);
                acc[1] = fmaf(wt, v.y, acc[1]);
                acc[2] = fmaf(wt, v.z, acc[2]);
                acc[3] = fmaf(wt, v.w, acc[3]);
            }
        }
        uint4 o;
        o.x = pack2(acc[0]); o.y = pack2(acc[1]);
        o.z = pack2(acc[2]); o.w = pack2(acc[3]);
        *(uint4*)&outp[(size_t)(pix0 + pix) * 256 + c4] = o;
    }
}

// ---------------------------------------------------------------------------
// Chunked pipeline. Per-image ws: 3 packed u32 planes (tO,tA,Xp) +
// offset f32 + attn f32 = 31.85 MB -> k=8 fits in ~255 MB.
// Vf (value, f32 HWC) aliases tA (dead after step 3); S (sampled, packed)
// reuses tO (dead after step 2). d_out written only by the final kernel.
// ---------------------------------------------------------------------------
extern "C" void kernel_launch(void* const* d_in, const int* in_sizes, int n_in,
                              void* d_out, int out_size, void* d_ws, size_t ws_size,
                              hipStream_t stream)
{
    const void* x        = d_in[0];
    const void* off_dw_w = d_in[1];
    const void* off_dw_b = d_in[2];
    const void* off_bn_g = d_in[3];
    const void* off_bn_b = d_in[4];
    const void* off_bn_m = d_in[5];
    const void* off_bn_v = d_in[6];
    const void* off_pw_w = d_in[7];
    const void* off_pw_b = d_in[8];
    const void* att_dw_w = d_in[9];
    const void* att_dw_b = d_in[10];
    const void* att_bn_g = d_in[11];
    const void* att_bn_b = d_in[12];
    const void* att_bn_m = d_in[13];
    const void* att_bn_v = d_in[14];
    const void* att_pw_w = d_in[15];
    const void* att_pw_b = d_in[16];
    const void* val_w    = d_in[17];
    const void* val_b    = d_in[18];
    const void* out_w    = d_in[19];
    const void* out_b    = d_in[20];

    const size_t perImg = 3 * IMG * 4          // packed u32 planes
                        + (size_t)HWp * 64 * 4 // offset fp32 HWC
                        + (size_t)HWp * 32 * 4;// attn fp32 HWC
    int k = 1;
    if      (ws_size >= 256 + 8 * perImg) k = 8;
    else if (ws_size >= 256 + 4 * perImg) k = 4;
    else if (ws_size >= 256 + 2 * perImg) k = 2;

    char* ws = (char*)d_ws;
    int*      flag = (int*)ws;
    const size_t kIMG = (size_t)k * IMG;
    unsigned* tO  = (unsigned*)(ws + 256);     // also S (sampled) after step 2
    unsigned* tA  = tO + kIMG;                 // also Vf (f32) after step 3
    unsigned* Xp  = tA + kIMG;
    float*    Vf  = (float*)tA;
    float*    OFF = (float*)(Xp + kIMG);
    float*    ATT = OFF + (size_t)k * HWp * 64;

    detect_dtype<<<1, 256, 0, stream>>>(x, flag);

    const int nPx  = k * 144;                  // 64-px GEMM tiles
    const int nDw  = k * 1152;                 // 8-px x 256-ch dwconv blocks
    const int nDef = k * (HWp / 16);

    for (int b0 = 0; b0 < Bn; b0 += k) {
        size_t xelem = (size_t)b0 * IMG;
        float* outp  = (float*)d_out + xelem;

        // 1. dwconv+BN+ReLU both branches; emit t_off/t_att/x packed HWC
        dwconv_bn_relu_hwc<<<nDw, 256, 0, stream>>>(
            x, xelem,
            off_dw_w, off_dw_b, off_bn_g, off_bn_b, off_bn_m, off_bn_v,
            att_dw_w, att_dw_b, att_bn_g, att_bn_b, att_bn_m, att_bn_v,
            tO, tA, Xp, flag);

        // 2. offset = t_off @ off_pw^T  (64 ch, HWC fp32)
        gemm_mfma<64, 0, false, true><<<nPx, 256, 0, stream>>>(
            tO, off_pw_w, off_pw_b, nullptr, 0, OFF, flag);

        // 3. attn = sigmoid(t_att @ att_pw^T)  (32 ch, HWC fp32; 2 waves)
        gemm_mfma<32, 1, false, true><<<nPx, 128, 0, stream>>>(
            tA, att_pw_w, att_pw_b, nullptr, 0, ATT, flag);

        // 4. value = x @ val_w^T  (256 ch, HWC fp32) -> Vf (aliases tA)
        gemm_mfma<256, 0, false, true><<<nPx * 4, 256, 0, stream>>>(
            Xp, val_w, val_b, nullptr, 0, Vf, flag);

        // 5. deformable sampling + attention sum -> S (reuses tO)
        deform_sample_hwc<<<nDef, 256, 0, stream>>>(Vf, OFF, ATT, tO);

        // 6. final projection + bias + residual -> d_out (fp32 CHW)
        gemm_mfma<256, 0, true, false><<<nPx * 4, 256, 0, stream>>>(
            tO, out_w, out_b, x, xelem, outp, flag);
    }
}

// Round 7
// 609.680 us; speedup vs baseline: 2.5375x; 1.2765x over previous
//
#include <hip/hip_runtime.h>
#include <hip/hip_bf16.h>

typedef __hip_bfloat16 bf16;

#define HWp 9216
#define Wd  96
#define Hd  96
#define Bn  8
#define Cn  256
#define IMG ((size_t)Cn * HWp)          // 2,359,296 elements per image

typedef __attribute__((ext_vector_type(8))) short        s16x8;
typedef __attribute__((ext_vector_type(8))) ushort       u16x8;
typedef __attribute__((ext_vector_type(8))) unsigned int u32x8;
typedef __attribute__((ext_vector_type(4))) float        f32x4;

// Load element i of a d_in-derived array; flag==1 -> fp32, flag==0 -> bf16.
__device__ __forceinline__ float ldf(const void* p, size_t i, int flag) {
    return flag ? ((const float*)p)[i] : __bfloat162float(((const bf16*)p)[i]);
}
template <int FLAG>
__device__ __forceinline__ float ldT(const void* p, size_t i) {
    return FLAG ? ((const float*)p)[i] : __bfloat162float(((const bf16*)p)[i]);
}

// fp32 -> bf16 bits, round-to-nearest-even (finite data only).
__device__ __forceinline__ ushort bf16_rne(float f) {
    unsigned u = __float_as_uint(f);
    unsigned r = (u + 0x7fffu + ((u >> 16) & 1u)) >> 16;
    return (ushort)r;
}
__device__ __forceinline__ float bf16_hi_f(ushort h) {
    return __uint_as_float((unsigned)h << 16);
}
// pack f into (hi_bf16 << 16) | lo_bf16, RNE both halves (~18-bit mantissa)
__device__ __forceinline__ unsigned pack2(float f) {
    ushort h = bf16_rne(f);
    ushort l = bf16_rne(f - bf16_hi_f(h));
    return ((unsigned)h << 16) | l;
}
// cheap pack: truncate hi, truncate residual lo (~14-bit mantissa, 5 VALU)
__device__ __forceinline__ unsigned packT(float f) {
    unsigned u  = __float_as_uint(f);
    unsigned hi = u & 0xffff0000u;
    float    r  = f - __uint_as_float(hi);
    return hi | (__float_as_uint(r) >> 16);
}

// ---------------------------------------------------------------------------
// Kernel 0: input dtype probe (fp32 expected; bf16 fallback kept as insurance)
// ---------------------------------------------------------------------------
__global__ void detect_dtype(const void* x, int* flag) {
    __shared__ int cnt;
    if (threadIdx.x == 0) cnt = 0;
    __syncthreads();
    const bf16* p = (const bf16*)x;
    int local = 0;
    #pragma unroll
    for (int k = 0; k < 16; ++k) {
        float w = __bfloat162float(p[threadIdx.x * 16 + k]);
        if (!(fabsf(w) < 1000.f)) local++;
    }
    atomicAdd(&cnt, local);
    __syncthreads();
    if (threadIdx.x == 0) *flag = (cnt > 64) ? 1 : 0;
}

// ---------------------------------------------------------------------------
// Kernel 1 v5: dwconv3x3 + BN + ReLU, both branches (unchanged from round 6).
// Block = one 8-px group x 256 channels (thread = channel). NO LDS; weights
// in registers; wave-uniform geometry; 3-row x 16-col float4 windows;
// 256B-contiguous packed stores.
// ---------------------------------------------------------------------------
template <int FLAG>
__device__ __forceinline__ void dw_body(
    const void* __restrict__ x, size_t xbase,
    const void* __restrict__ ow, const void* __restrict__ obias,
    const void* __restrict__ og, const void* __restrict__ obeta,
    const void* __restrict__ om, const void* __restrict__ ov,
    const void* __restrict__ aw, const void* __restrict__ abias,
    const void* __restrict__ ag, const void* __restrict__ abeta,
    const void* __restrict__ am, const void* __restrict__ av,
    unsigned* __restrict__ tO, unsigned* __restrict__ tA,
    unsigned* __restrict__ Xp)
{
    const int G   = gridDim.x;                       // k*1152, multiple of 8
    const int nb  = (blockIdx.x & 7) * (G >> 3) + (blockIdx.x >> 3);
    const int c   = threadIdx.x;                     // channel 0..255
    const int img = nb / 1152;
    const int gl  = nb % 1152;
    const int i   = gl / 12;                         // row (wave-uniform)
    const int j0  = (gl % 12) * 8;                   // col base (wave-uniform)

    // ---- per-channel params in registers
    float wo[9], wa[9];
    #pragma unroll
    for (int k = 0; k < 9; ++k) {
        wo[k] = ldT<FLAG>(ow, (size_t)c * 9 + k);
        wa[k] = ldT<FLAG>(aw, (size_t)c * 9 + k);
    }
    float sco = ldT<FLAG>(og, c) * rsqrtf(ldT<FLAG>(ov, c) + 1e-5f);
    float sho = (ldT<FLAG>(obias, c) - ldT<FLAG>(om, c)) * sco + ldT<FLAG>(obeta, c);
    float sca = ldT<FLAG>(ag, c) * rsqrtf(ldT<FLAG>(av, c) + 1e-5f);
    float sha = (ldT<FLAG>(abias, c) - ldT<FLAG>(am, c)) * sca + ldT<FLAG>(abeta, c);

    // row-edge masks folded into weights (wave-uniform branches)
    if (i == 0)      { wo[0]=wo[1]=wo[2]=0.f; wa[0]=wa[1]=wa[2]=0.f; }
    if (i == Hd - 1) { wo[6]=wo[7]=wo[8]=0.f; wa[6]=wa[7]=wa[8]=0.f; }

    // ---- load 3 rows x 16-col windows; w3[r][idx] = col (j0-4+idx)
    const size_t plane = xbase + (size_t)img * IMG + (size_t)c * HWp;
    const int c00 = (j0 == 0)  ? 0  : j0 - 4;        // wave-uniform
    const int c03 = (j0 == 88) ? 92 : j0 + 8;
    float w3[3][16];
    #pragma unroll
    for (int r3 = 0; r3 < 3; ++r3) {
        int rr = min(max(i - 1 + r3, 0), Hd - 1);
        size_t rb = plane + (size_t)rr * Wd;
        if (FLAG) {
            *(float4*)&w3[r3][0]  = *(const float4*)((const float*)x + rb + c00);
            *(float4*)&w3[r3][4]  = *(const float4*)((const float*)x + rb + j0);
            *(float4*)&w3[r3][8]  = *(const float4*)((const float*)x + rb + j0 + 4);
            *(float4*)&w3[r3][12] = *(const float4*)((const float*)x + rb + c03);
        } else {
            #pragma unroll
            for (int t = 0; t < 4; ++t) {
                w3[r3][t]      = ldT<FLAG>(x, rb + c00 + t);
                w3[r3][4 + t]  = ldT<FLAG>(x, rb + j0 + t);
                w3[r3][8 + t]  = ldT<FLAG>(x, rb + j0 + 4 + t);
                w3[r3][12 + t] = ldT<FLAG>(x, rb + c03 + t);
            }
        }
    }
    // col-edge masks
    if (j0 == 0)  { w3[0][3]  = 0.f; w3[1][3]  = 0.f; w3[2][3]  = 0.f; }
    if (j0 == 88) { w3[0][12] = 0.f; w3[1][12] = 0.f; w3[2][12] = 0.f; }

    // ---- compute 8 px, pack
    unsigned ro[8], ra[8], rx[8];
    #pragma unroll
    for (int p = 0; p < 8; ++p) {
        float so = 0.f, sa = 0.f;
        #pragma unroll
        for (int r3 = 0; r3 < 3; ++r3) {
            #pragma unroll
            for (int dj = 0; dj < 3; ++dj) {
                float xv = w3[r3][3 + p + dj];       // static idx 3..12
                so = fmaf(xv, wo[r3 * 3 + dj], so);
                sa = fmaf(xv, wa[r3 * 3 + dj], sa);
            }
        }
        float to = fmaxf(fmaf(so, sco, sho), 0.f);
        float ta = fmaxf(fmaf(sa, sca, sha), 0.f);
        ro[p] = packT(to);
        ra[p] = packT(ta);
        rx[p] = packT(w3[1][4 + p]);                 // center tap = x itself
    }

    // ---- stores: lane=c -> 256B contiguous per inst, full rows per block
    const size_t ob = (size_t)nb * 8 * 256 + c;
    #pragma unroll
    for (int p = 0; p < 8; ++p) {
        tO[ob + p * 256] = ro[p];
        tA[ob + p * 256] = ra[p];
        Xp[ob + p * 256] = rx[p];
    }
}

__global__ __launch_bounds__(256) void dwconv_bn_relu_hwc(
    const void* __restrict__ x, size_t xbase,
    const void* __restrict__ ow, const void* __restrict__ obias,
    const void* __restrict__ og, const void* __restrict__ obeta,
    const void* __restrict__ om, const void* __restrict__ ov,
    const void* __restrict__ aw, const void* __restrict__ abias,
    const void* __restrict__ ag, const void* __restrict__ abeta,
    const void* __restrict__ am, const void* __restrict__ av,
    unsigned* __restrict__ tO, unsigned* __restrict__ tA,
    unsigned* __restrict__ Xp, const int* __restrict__ flagp)
{
    if (*flagp)
        dw_body<1>(x, xbase, ow, obias, og, obeta, om, ov,
                   aw, abias, ag, abeta, am, av, tO, tA, Xp);
    else
        dw_body<0>(x, xbase, ow, obias, og, obeta, om, ov,
                   aw, abias, ag, abeta, am, av, tO, tA, Xp);
}

// ---------------------------------------------------------------------------
// MFMA 1x1-conv GEMM v2: LDS-staged A tile (guide §5 canonical structure).
// A: packed u32 plane [px][256]. Per block: stage 64 px x 256 ch = 64 KB
// into LDS (wave-uniform row, 1 KB coalesced global read per wave-inst,
// ds_write_b128 with chunk swizzle c^=(r&7)); barrier; fragments via
// ds_read_b128 (~120cy, conflict-free at b128 baseline) -> kills the L2
// latency that pinned round-6's GEMM at MfmaUtil 5.4%.
// COUT=256: 8 waves, 128 outs/block (A staged once for 8 waves).
// COUT=64: 4 waves. COUT=32: 2 waves. bf16x2 split: 3 MFMAs/k-tile.
// A-frag/B-frag transposed lane layouts -> swapped operands give D^T
// (CHW-output final conv with residual).
// ---------------------------------------------------------------------------
template <int COUT, int ACT, bool RES, bool OUTHWC>
__global__ __launch_bounds__(COUT >= 256 ? 512 : (COUT / 16) * 64)
void gemm_mfma(
    const unsigned* __restrict__ Ap,
    const void* __restrict__ w, const void* __restrict__ bias,
    const void* __restrict__ res, size_t res_base,
    float* __restrict__ out, const int* __restrict__ flagp)
{
    constexpr int NW = (COUT >= 256) ? 8 : COUT / 16;   // waves per block
    __shared__ unsigned sA[64 * 256];                   // 64 KB

    const int flag = *flagp;
    const int tid  = threadIdx.x;
    const int lane = tid & 63;
    const int wv   = tid >> 6;

    int pt, og;
    if constexpr (COUT >= 256) { pt = blockIdx.x >> 1; og = blockIdx.x & 1; }
    else                       { pt = blockIdx.x;      og = 0; }
    const int px0 = pt * 64;
    const int ob  = og * 128 + wv * 16;

    const int lr = lane & 15;
    const int lk = lane >> 4;

    // ---- weight fragments, hi/lo (issued first; overlap with staging)
    s16x8 wh[8], wl[8];
    {
        const size_t wrow = (size_t)(ob + lr) * 256 + lk * 8;
        #pragma unroll
        for (int kk = 0; kk < 8; ++kk) {
            float f[8];
            if (flag) {
                float4 v0 = *(const float4*)((const float*)w + wrow + kk * 32);
                float4 v1 = *(const float4*)((const float*)w + wrow + kk * 32 + 4);
                f[0]=v0.x; f[1]=v0.y; f[2]=v0.z; f[3]=v0.w;
                f[4]=v1.x; f[5]=v1.y; f[6]=v1.z; f[7]=v1.w;
            } else {
                #pragma unroll
                for (int i = 0; i < 8; ++i)
                    f[i] = __bfloat162float(((const bf16*)w)[wrow + kk * 32 + i]);
            }
            #pragma unroll
            for (int i = 0; i < 8; ++i) {
                ushort h = bf16_rne(f[i]);
                wh[kk][i] = (short)h;
                wl[kk][i] = (short)bf16_rne(f[i] - bf16_hi_f(h));
            }
        }
    }

    // ---- stage A tile: row r (wave-uniform) -> LDS[r][chunk lane ^ (r&7)]
    {
        const unsigned* src = Ap + (size_t)px0 * 256;
        #pragma unroll
        for (int s = 0; s < 64 / NW; ++s) {
            int r = s * NW + wv;
            uint4 v = *(const uint4*)(src + (size_t)r * 256 + lane * 4);
            int  c  = lane ^ (r & 7);
            *(uint4*)&sA[r * 256 + c * 4] = v;
        }
    }
    __syncthreads();

    // ---- compute: fragments from LDS (chunk c = 8*kk + 2*lk + h, swizzled)
    f32x4 acc[4] = {};
    #pragma unroll
    for (int m = 0; m < 4; ++m) {
        const int r = m * 16 + lr;
        const unsigned* rowp = &sA[r * 256];
        const int sw = r & 7;
        #pragma unroll
        for (int kk = 0; kk < 8; ++kk) {
            uint4 v0 = *(const uint4*)(rowp + (((8 * kk + 2 * lk)     ^ sw) * 4));
            uint4 v1 = *(const uint4*)(rowp + (((8 * kk + 2 * lk + 1) ^ sw) * 4));
            unsigned u[8] = {v0.x, v0.y, v0.z, v0.w, v1.x, v1.y, v1.z, v1.w};
            s16x8 ah, al;
            #pragma unroll
            for (int i = 0; i < 8; ++i) {
                ah[i] = (short)(u[i] >> 16);
                al[i] = (short)(u[i] & 0xffffu);
            }
            if (OUTHWC) {
                acc[m] = __builtin_amdgcn_mfma_f32_16x16x32_bf16(ah, wh[kk], acc[m], 0, 0, 0);
                acc[m] = __builtin_amdgcn_mfma_f32_16x16x32_bf16(ah, wl[kk], acc[m], 0, 0, 0);
                acc[m] = __builtin_amdgcn_mfma_f32_16x16x32_bf16(al, wh[kk], acc[m], 0, 0, 0);
            } else {
                acc[m] = __builtin_amdgcn_mfma_f32_16x16x32_bf16(wh[kk], ah, acc[m], 0, 0, 0);
                acc[m] = __builtin_amdgcn_mfma_f32_16x16x32_bf16(wl[kk], ah, acc[m], 0, 0, 0);
                acc[m] = __builtin_amdgcn_mfma_f32_16x16x32_bf16(wh[kk], al, acc[m], 0, 0, 0);
            }
        }
    }

    if (OUTHWC) {
        // D: row=px (lk*4+r within m-frag), col=o (lr)
        int o = ob + lr;
        float bv = ldf(bias, o, flag);
        #pragma unroll
        for (int m = 0; m < 4; ++m) {
            #pragma unroll
            for (int r = 0; r < 4; ++r) {
                int px = px0 + m * 16 + lk * 4 + r;
                float v = acc[m][r] + bv;
                if (ACT == 1) v = 1.f / (1.f + __expf(-v));
                out[(size_t)px * COUT + o] = v;
            }
        }
    } else {
        // Swapped operands: D row=o (lk*4+r), col=px (lr). CHW out + residual.
        int img = px0 / HWp;
        int hwb = px0 % HWp;
        #pragma unroll
        for (int r = 0; r < 4; ++r) {
            int o = ob + lk * 4 + r;
            float bv = ldf(bias, o, flag);
            #pragma unroll
            for (int m = 0; m < 4; ++m) {
                int hw = hwb + m * 16 + lr;
                size_t oidx = (size_t)img * IMG + (size_t)o * HWp + hw;
                float v = acc[m][r] + bv;
                if (RES) v += ldf(res, res_base + oidx, flag);
                out[oidx] = v;
            }
        }
    }
}

// ---------------------------------------------------------------------------
// Kernel 5 v4: deformable bilinear sampling + attention sum, channel-last.
// (unchanged from round 6)
// ---------------------------------------------------------------------------
__global__ __launch_bounds__(256) void deform_sample_hwc(
    const float* __restrict__ value,
    const float* __restrict__ offset,
    const float* __restrict__ attn,
    unsigned* __restrict__ outp)
{
    __shared__ int   sIdx[16 * 32 * 4];   // [pix][n*4+p][tap]
    __shared__ float sWt [16 * 32 * 4];

    int tid  = threadIdx.x;
    const int G  = gridDim.x;                          // multiple of 8
    const int nb = (blockIdx.x & 7) * (G >> 3) + (blockIdx.x >> 3);
    int pix0 = nb * 16;                                // chunk-local pixel base

    // ---- phase 1: tap precompute --------------------------------------
    #pragma unroll
    for (int it = 0; it < 2; ++it) {
        int task = it * 256 + tid;        // 512 tasks
        int pix  = task >> 5;             // 0..15
        int np   = task & 31;             // n*4+p
        int gpix = pix0 + pix;
        int hw   = gpix % HWp;
        int i    = hw / Wd;
        int j    = hw % Wd;
        float ox = offset[(size_t)gpix * 64 + np * 2];
        float oy = offset[(size_t)gpix * 64 + np * 2 + 1];
        float a  = attn[(size_t)gpix * 32 + np];
        float ix = (float)j + 0.5f + ox * 47.5f;
        float iy = (float)i + 0.5f + oy * 47.5f;
        float x0 = floorf(ix), y0 = floorf(iy);
        float wx1 = ix - x0, wy1 = iy - y0;
        float wx0 = 1.f - wx1, wy0 = 1.f - wy1;
        int base = task * 4;
        #pragma unroll
        for (int t = 0; t < 4; ++t) {
            float xc = (t & 1) ? x0 + 1.f : x0;
            float yc = (t & 2) ? y0 + 1.f : y0;
            float wt = ((t & 1) ? wx1 : wx0) * ((t & 2) ? wy1 : wy0);
            bool ok  = (xc >= 0.f) & (xc <= 95.f) & (yc >= 0.f) & (yc <= 95.f);
            int xi = min(max((int)xc, 0), 95);
            int yi = min(max((int)yc, 0), 95);
            sIdx[base + t] = yi * Wd + xi;
            sWt [base + t] = ok ? a * wt : 0.f;
        }
    }
    __syncthreads();

    // ---- phase 2: vectorized gather + accumulate ----------------------
    const int lane = tid & 63;
    const int wvv  = tid >> 6;
    const int c4   = lane * 4;            // 4 consecutive channels
    const int n    = lane >> 3;           // head = c4>>5
    const int img  = pix0 / HWp;          // tiles never cross image
    const float* vbase = value + (size_t)img * HWp * 256;

    #pragma unroll
    for (int pi = 0; pi < 4; ++pi) {
        int pix  = wvv * 4 + pi;
        int base = (pix * 32 + n * 4) * 4;
        f32x4 acc = {};
        #pragma unroll
        for (int p = 0; p < 4; ++p) {
            #pragma unroll
            for (int t = 0; t < 4; ++t) {
                float wt = sWt [base + p * 4 + t];
                int   ix = sIdx[base + p * 4 + t];
                float4 v = *(const float4*)&vbase[(size_t)ix * 256 + c4];
                acc[0] = fmaf(wt, v.x, acc[0]);
                acc[1] = fmaf(wt, v.y, acc[1]);
                acc[2] = fmaf(wt, v.z, acc[2]);
                acc[3] = fmaf(wt, v.w, acc[3]);
            }
        }
        uint4 o;
        o.x = pack2(acc[0]); o.y = pack2(acc[1]);
        o.z = pack2(acc[2]); o.w = pack2(acc[3]);
        *(uint4*)&outp[(size_t)(pix0 + pix) * 256 + c4] = o;
    }
}

// ---------------------------------------------------------------------------
// Chunked pipeline. Per-image ws: 3 packed u32 planes (tO,tA,Xp) +
// offset f32 + attn f32 = 31.85 MB -> k=8 fits in ~255 MB.
// Vf (value, f32 HWC) aliases tA (dead after step 3); S (sampled, packed)
// reuses tO (dead after step 2). d_out written only by the final kernel.
// ---------------------------------------------------------------------------
extern "C" void kernel_launch(void* const* d_in, const int* in_sizes, int n_in,
                              void* d_out, int out_size, void* d_ws, size_t ws_size,
                              hipStream_t stream)
{
    const void* x        = d_in[0];
    const void* off_dw_w = d_in[1];
    const void* off_dw_b = d_in[2];
    const void* off_bn_g = d_in[3];
    const void* off_bn_b = d_in[4];
    const void* off_bn_m = d_in[5];
    const void* off_bn_v = d_in[6];
    const void* off_pw_w = d_in[7];
    const void* off_pw_b = d_in[8];
    const void* att_dw_w = d_in[9];
    const void* att_dw_b = d_in[10];
    const void* att_bn_g = d_in[11];
    const void* att_bn_b = d_in[12];
    const void* att_bn_m = d_in[13];
    const void* att_bn_v = d_in[14];
    const void* att_pw_w = d_in[15];
    const void* att_pw_b = d_in[16];
    const void* val_w    = d_in[17];
    const void* val_b    = d_in[18];
    const void* out_w    = d_in[19];
    const void* out_b    = d_in[20];

    const size_t perImg = 3 * IMG * 4          // packed u32 planes
                        + (size_t)HWp * 64 * 4 // offset fp32 HWC
                        + (size_t)HWp * 32 * 4;// attn fp32 HWC
    int k = 1;
    if      (ws_size >= 256 + 8 * perImg) k = 8;
    else if (ws_size >= 256 + 4 * perImg) k = 4;
    else if (ws_size >= 256 + 2 * perImg) k = 2;

    char* ws = (char*)d_ws;
    int*      flag = (int*)ws;
    const size_t kIMG = (size_t)k * IMG;
    unsigned* tO  = (unsigned*)(ws + 256);     // also S (sampled) after step 2
    unsigned* tA  = tO + kIMG;                 // also Vf (f32) after step 3
    unsigned* Xp  = tA + kIMG;
    float*    Vf  = (float*)tA;
    float*    OFF = (float*)(Xp + kIMG);
    float*    ATT = OFF + (size_t)k * HWp * 64;

    detect_dtype<<<1, 256, 0, stream>>>(x, flag);

    const int nPx  = k * 144;                  // 64-px GEMM tiles
    const int nDw  = k * 1152;                 // 8-px x 256-ch dwconv blocks
    const int nDef = k * (HWp / 16);

    for (int b0 = 0; b0 < Bn; b0 += k) {
        size_t xelem = (size_t)b0 * IMG;
        float* outp  = (float*)d_out + xelem;

        // 1. dwconv+BN+ReLU both branches; emit t_off/t_att/x packed HWC
        dwconv_bn_relu_hwc<<<nDw, 256, 0, stream>>>(
            x, xelem,
            off_dw_w, off_dw_b, off_bn_g, off_bn_b, off_bn_m, off_bn_v,
            att_dw_w, att_dw_b, att_bn_g, att_bn_b, att_bn_m, att_bn_v,
            tO, tA, Xp, flag);

        // 2. offset = t_off @ off_pw^T  (64 ch, HWC fp32; 4 waves)
        gemm_mfma<64, 0, false, true><<<nPx, 256, 0, stream>>>(
            tO, off_pw_w, off_pw_b, nullptr, 0, OFF, flag);

        // 3. attn = sigmoid(t_att @ att_pw^T)  (32 ch, HWC fp32; 2 waves)
        gemm_mfma<32, 1, false, true><<<nPx, 128, 0, stream>>>(
            tA, att_pw_w, att_pw_b, nullptr, 0, ATT, flag);

        // 4. value = x @ val_w^T  (256 ch, HWC fp32) -> Vf (aliases tA)
        gemm_mfma<256, 0, false, true><<<nPx * 2, 512, 0, stream>>>(
            Xp, val_w, val_b, nullptr, 0, Vf, flag);

        // 5. deformable sampling + attention sum -> S (reuses tO)
        deform_sample_hwc<<<nDef, 256, 0, stream>>>(Vf, OFF, ATT, tO);

        // 6. final projection + bias + residual -> d_out (fp32 CHW)
        gemm_mfma<256, 0, true, false><<<nPx * 2, 512, 0, stream>>>(
            tO, out_w, out_b, x, xelem, outp, flag);
    }
}